// Round 1
// baseline (3404.624 us; speedup 1.0000x reference)
//
#include <hip/hip_runtime.h>
#include <hip/hip_bf16.h>
#include <math.h>
#include <cstddef>

namespace {

constexpr int kB   = 128;
constexpr int kS   = 256;
constexpr int kD   = 768;   // multiple of 32
constexpr int kSP  = 257;
constexpr int kN   = kB * kSP;   // 32896 = 257*128
constexpr int kARC = 500;
constexpr int kTAG = 100;
constexpr int KA   = 512;   // padded K for ARC features / T
constexpr int KT   = 128;   // padded K for TAG features

typedef __attribute__((ext_vector_type(8))) short short8;
typedef __attribute__((ext_vector_type(4))) float floatx4;
typedef __attribute__((ext_vector_type(2))) float floatx2;
typedef __attribute__((ext_vector_type(4))) unsigned short ushort4v;
typedef __attribute__((ext_vector_type(2))) unsigned short ushort2v;
typedef __hip_bfloat16 bf;

__device__ __forceinline__ float bfval(bf h) { return __bfloat162float(h); }
__device__ __forceinline__ unsigned short bfbits(bf h) {
  unsigned short u; __builtin_memcpy(&u, &h, 2); return u;
}
__device__ __forceinline__ void splitf(float x, bf* h, bf* l) {
  bf hh = __float2bfloat16(x);
  *h = hh;
  *l = __float2bfloat16(x - __bfloat162float(hh));
}

// async global -> LDS, 16B per lane; LDS dest is wave-uniform base + lane*16
__device__ __forceinline__ void gload16(const bf* g, bf* l) {
  __builtin_amdgcn_global_load_lds(
      (const __attribute__((address_space(1))) void*)g,
      (__attribute__((address_space(3))) void*)l, 16, 0, 0);
}

// ---------- per-tensor dtype detection (1 = bf16 storage, 0 = fp32) ----------
__global__ void detect_dtype_n(const unsigned* __restrict__ raw, int* __restrict__ flag,
                               int nwords) {
  int lane = threadIdx.x;
  int ok = 0, nz = 0;
  if (lane < nwords) {
    unsigned w = raw[lane];
    if (w != 0u) {
      nz = 1;
      int e = (w >> 7) & 0xFF;
      ok = (e >= 90 && e <= 140);
    }
  }
  unsigned long long ball_ok = __ballot(ok);
  unsigned long long ball_nz = __ballot(nz);
  if (lane == 0) {
    int cok = __popcll(ball_ok), cnz = __popcll(ball_nz);
    flag[0] = (cok * 4 >= cnz * 3) ? 1 : 0;
  }
}

__device__ __forceinline__ float rawload(const void* p, size_t i, int bfm) {
  return bfm ? __bfloat162float(((const bf*)p)[i]) : ((const float*)p)[i];
}

// fp32 canonicalize with element offset
__global__ void conv_off(const void* __restrict__ src, float* __restrict__ dst,
                         int n, long off, const int* __restrict__ flag) {
  int i = blockIdx.x * 256 + threadIdx.x;
  if (i >= n) return;
  dst[i] = rawload(src, (size_t)off + i, *flag);
}

// transpose + split weight: raw W[K][N] (row stride ldsrc) -> Wh/Wl [N][Kpad], zero pad
__global__ void wsplit_t(const void* __restrict__ src, const int* __restrict__ flag,
                         long srcOff, int ldsrc, int K, int N, int Kpad,
                         bf* __restrict__ Wh, bf* __restrict__ Wl) {
  long idx = (long)blockIdx.x * 256 + threadIdx.x;
  if (idx >= (long)N * Kpad) return;
  int n = (int)(idx / Kpad), k = (int)(idx % Kpad);
  float v = (k < K) ? rawload(src, (size_t)srcOff + (size_t)k * ldsrc + n, *flag) : 0.f;
  bf h, l;
  splitf(v, &h, &l);
  Wh[idx] = h; Wl[idx] = l;
}

// ---------- x split: sentinel-fused input -> xh/xl [NG][768] ----------
__global__ void xsplit(const void* __restrict__ inp, const void* __restrict__ sent,
                       const int* __restrict__ fi, const int* __restrict__ fs,
                       bf* __restrict__ xh, bf* __restrict__ xl, int g0, int NG) {
  long idx = (long)blockIdx.x * 256 + threadIdx.x;   // one quad of elements
  long tot = (long)NG * (kD / 4);
  if (idx >= tot) return;
  int n = (int)(idx / (kD / 4));
  int k = (int)(idx % (kD / 4)) * 4;
  int b = n / kSP, r = n - b * kSP;
  const void* src;
  size_t base;
  int bfm;
  if (r == 0) { src = sent; base = (size_t)k; bfm = *fs; }
  else {
    src = inp;
    base = ((size_t)((g0 + b) * kS + (r - 1))) * kD + k;
    bfm = *fi;
  }
  float v[4];
  if (bfm) {
    ushort4v s = *(const ushort4v*)((const unsigned short*)src + base);
#pragma unroll
    for (int j = 0; j < 4; ++j) {
      bf h; unsigned short u = s[j];
      __builtin_memcpy(&h, &u, 2);
      v[j] = __bfloat162float(h);
    }
  } else {
    floatx4 f4 = *(const floatx4*)((const float*)src + base);
#pragma unroll
    for (int j = 0; j < 4; ++j) v[j] = f4[j];
  }
  ushort4v h4, l4;
#pragma unroll
  for (int j = 0; j < 4; ++j) {
    bf h, l;
    splitf(v[j], &h, &l);
    h4[j] = bfbits(h); l4[j] = bfbits(l);
  }
  size_t o = (size_t)n * kD + k;
  *(ushort4v*)((unsigned short*)xh + o) = h4;
  *(ushort4v*)((unsigned short*)xl + o) = l4;
}

// =================== split-bf16 MFMA GEMM, global_load_lds staging ===================
// C[M,N] = act( sum_k (Ah+Al)[m,k]*(Bh+Bl)[n,k] + bias[n]? )  (drop lo*lo)
// EPI: 0 none, 1 bias+elu, 2 bias.  OUTF32: 1 -> Cf fp32 (no pad writes),
//                                   0 -> split planes Ch/Cl with [N,ldc) zeroed.
constexpr int BM = 128, BN = 128, BK = 32;

template <int EPI, int OUTF32>
__global__ __launch_bounds__(256) void gemm_sp(
    const bf* __restrict__ Ah, const bf* __restrict__ Al, int lda,
    const bf* __restrict__ Bh, const bf* __restrict__ Bl, int ldb,
    bf* __restrict__ Ch, bf* __restrict__ Cl, float* __restrict__ Cf, int ldc,
    int M, int N, int K, const float* __restrict__ bias) {
  __shared__ bf sAh[BM][BK];
  __shared__ bf sAl[BM][BK];
  __shared__ bf sBh[BN][BK];
  __shared__ bf sBl[BN][BK];
  const int tid = threadIdx.x;
  const int lane = tid & 63, wave = tid >> 6;
  const int quad = lane >> 4, l15 = lane & 15;
  const int wm = (wave >> 1) * 64, wn = (wave & 1) * 64;
  const int m0 = blockIdx.x * BM, n0 = blockIdx.y * BN;
  const int lrow = lane >> 2, lkof = (lane & 3) * 8;

  // per-lane global bases (row-clamped; garbage lands only in discarded C rows/cols)
  const bf *pAh[2], *pAl[2], *pBh[2], *pBl[2];
#pragma unroll
  for (int jj = 0; jj < 2; ++jj) {
    int rb = wave * 32 + jj * 16;
    int gm = m0 + rb + lrow; if (gm > M - 1) gm = M - 1;
    int gn = n0 + rb + lrow; if (gn > N - 1) gn = N - 1;
    pAh[jj] = Ah + (size_t)gm * lda + lkof;
    pAl[jj] = Al + (size_t)gm * lda + lkof;
    pBh[jj] = Bh + (size_t)gn * ldb + lkof;
    pBl[jj] = Bl + (size_t)gn * ldb + lkof;
  }

  floatx4 acc[4][4] = {};
  for (int k0 = 0; k0 < K; k0 += BK) {
#pragma unroll
    for (int jj = 0; jj < 2; ++jj) {
      const int rb = wave * 32 + jj * 16;
      gload16(pAh[jj] + k0, &sAh[rb][0]);
      gload16(pAl[jj] + k0, &sAl[rb][0]);
      gload16(pBh[jj] + k0, &sBh[rb][0]);
      gload16(pBl[jj] + k0, &sBl[rb][0]);
    }
    __syncthreads();
    short8 a_h[4], a_l[4], b_h[4], b_l[4];
#pragma unroll
    for (int t = 0; t < 4; ++t) {
      a_h[t] = *(const short8*)&sAh[wm + t * 16 + l15][quad * 8];
      a_l[t] = *(const short8*)&sAl[wm + t * 16 + l15][quad * 8];
      b_h[t] = *(const short8*)&sBh[wn + t * 16 + l15][quad * 8];
      b_l[t] = *(const short8*)&sBl[wn + t * 16 + l15][quad * 8];
    }
#pragma unroll
    for (int mt = 0; mt < 4; ++mt)
#pragma unroll
      for (int nt = 0; nt < 4; ++nt) {
        acc[mt][nt] = __builtin_amdgcn_mfma_f32_16x16x32_bf16(a_h[mt], b_h[nt], acc[mt][nt], 0, 0, 0);
        acc[mt][nt] = __builtin_amdgcn_mfma_f32_16x16x32_bf16(a_h[mt], b_l[nt], acc[mt][nt], 0, 0, 0);
        acc[mt][nt] = __builtin_amdgcn_mfma_f32_16x16x32_bf16(a_l[mt], b_h[nt], acc[mt][nt], 0, 0, 0);
      }
    __syncthreads();
  }
#pragma unroll
  for (int mt = 0; mt < 4; ++mt)
#pragma unroll
    for (int reg = 0; reg < 4; ++reg) {
      int m = m0 + wm + mt * 16 + quad * 4 + reg;
      if (m >= M) continue;
#pragma unroll
      for (int nt = 0; nt < 4; ++nt) {
        int n = n0 + wn + nt * 16 + l15;
        if (OUTF32) {
          if (n < N) {
            float v = acc[mt][nt][reg];
            if (EPI >= 1) v += bias[n];
            if (EPI == 1) v = v > 0.f ? v : expm1f(v);
            Cf[(size_t)m * ldc + n] = v;
          }
        } else {
          size_t o = (size_t)m * ldc + n;
          if (n < N) {
            float v = acc[mt][nt][reg];
            if (EPI >= 1) v += bias[n];
            if (EPI == 1) v = v > 0.f ? v : expm1f(v);
            bf h, l;
            splitf(v, &h, &l);
            Ch[o] = h; Cl[o] = l;
          } else if (n < ldc) {
            Ch[o] = __float2bfloat16(0.f);
            Cl[o] = __float2bfloat16(0.f);
          }
        }
      }
    }
}

// ====== batched NT bilinear, global_load_lds staging; out fp32 +rowterm +bilb ======
__global__ __launch_bounds__(256) void bilnt_sp(
    const bf* __restrict__ Th, const bf* __restrict__ Tl,  // [GB*257][512]
    const bf* __restrict__ Fh, const bf* __restrict__ Fl,  // featDA
    float* __restrict__ out, const float* __restrict__ bilb, int bidx,
    int g0, int globOut) {
  __shared__ bf sAh[BM][BK];
  __shared__ bf sAl[BM][BK];
  __shared__ bf sBh[BN][BK];
  __shared__ bf sBl[BN][BK];
  const int z = blockIdx.z;
  const int tid = threadIdx.x;
  const int lane = tid & 63, wave = tid >> 6;
  const int quad = lane >> 4, l15 = lane & 15;
  const int wm = (wave >> 1) * 64, wn = (wave & 1) * 64;
  const int m0 = blockIdx.x * BM, n0 = blockIdx.y * BN;
  const int lrow = lane >> 2, lkof = (lane & 3) * 8;
  const bf* Ah = Th + (size_t)z * kSP * KA;
  const bf* Al = Tl + (size_t)z * kSP * KA;
  const bf* Bh = Fh + (size_t)z * kSP * KA;
  const bf* Bl = Fl + (size_t)z * kSP * KA;

  const bf *pAh[2], *pAl[2], *pBh[2], *pBl[2];
#pragma unroll
  for (int jj = 0; jj < 2; ++jj) {
    int rb = wave * 32 + jj * 16;
    int gm = m0 + rb + lrow; if (gm > kSP - 1) gm = kSP - 1;
    int gn = n0 + rb + lrow; if (gn > kSP - 1) gn = kSP - 1;
    pAh[jj] = Ah + (size_t)gm * KA + lkof;
    pAl[jj] = Al + (size_t)gm * KA + lkof;
    pBh[jj] = Bh + (size_t)gn * KA + lkof;
    pBl[jj] = Bl + (size_t)gn * KA + lkof;
  }

  floatx4 acc[4][4] = {};
  for (int k0 = 0; k0 < KA; k0 += BK) {
#pragma unroll
    for (int jj = 0; jj < 2; ++jj) {
      const int rb = wave * 32 + jj * 16;
      gload16(pAh[jj] + k0, &sAh[rb][0]);
      gload16(pAl[jj] + k0, &sAl[rb][0]);
      gload16(pBh[jj] + k0, &sBh[rb][0]);
      gload16(pBl[jj] + k0, &sBl[rb][0]);
    }
    __syncthreads();
    short8 a_h[4], a_l[4], b_h[4], b_l[4];
#pragma unroll
    for (int t = 0; t < 4; ++t) {
      a_h[t] = *(const short8*)&sAh[wm + t * 16 + l15][quad * 8];
      a_l[t] = *(const short8*)&sAl[wm + t * 16 + l15][quad * 8];
      b_h[t] = *(const short8*)&sBh[wn + t * 16 + l15][quad * 8];
      b_l[t] = *(const short8*)&sBl[wn + t * 16 + l15][quad * 8];
    }
#pragma unroll
    for (int mt = 0; mt < 4; ++mt)
#pragma unroll
      for (int nt = 0; nt < 4; ++nt) {
        acc[mt][nt] = __builtin_amdgcn_mfma_f32_16x16x32_bf16(a_h[mt], b_h[nt], acc[mt][nt], 0, 0, 0);
        acc[mt][nt] = __builtin_amdgcn_mfma_f32_16x16x32_bf16(a_h[mt], b_l[nt], acc[mt][nt], 0, 0, 0);
        acc[mt][nt] = __builtin_amdgcn_mfma_f32_16x16x32_bf16(a_l[mt], b_h[nt], acc[mt][nt], 0, 0, 0);
      }
    __syncthreads();
  }
  const float sb = bilb[bidx];
  const int bb = globOut ? (g0 + z) : z;
#pragma unroll
  for (int mt = 0; mt < 4; ++mt)
#pragma unroll
    for (int reg = 0; reg < 4; ++reg) {
      int i = m0 + wm + mt * 16 + quad * 4 + reg;
      if (i >= kSP) continue;
      float rowterm = bfval(Ah[(size_t)i * KA + 500]) + bfval(Al[(size_t)i * KA + 500]) + sb;
#pragma unroll
      for (int nt = 0; nt < 4; ++nt) {
        int j = n0 + wn + nt * 16 + l15;
        if (j >= kSP) continue;
        out[((size_t)bb * kSP + i) * kSP + j] = acc[mt][nt][reg] + rowterm;
      }
    }
}

// ------------- per-row softmax + top-8 (+dinv); one wave per row -------------
__global__ void softmax_topk(const float* __restrict__ logits,
                             int* __restrict__ idx8,
                             float* __restrict__ val8,
                             float* __restrict__ dinv) {
  const int row = blockIdx.x;
  const int lane = threadIdx.x;
  const int rowbase = row - (row % kSP);
  const float* L = logits + (size_t)row * kSP;
  float v[5];
  int c[5];
#pragma unroll
  for (int q = 0; q < 5; ++q) {
    int j = lane + q * 64;
    c[q] = j;
    v[q] = (j < kSP) ? L[j] : -INFINITY;
  }
  float m = v[0];
#pragma unroll
  for (int q = 1; q < 5; ++q) m = fmaxf(m, v[q]);
  for (int off = 32; off > 0; off >>= 1) m = fmaxf(m, __shfl_xor(m, off));
  float s = 0.f;
#pragma unroll
  for (int q = 0; q < 5; ++q) s += expf(v[q] - m);
  for (int off = 32; off > 0; off >>= 1) s += __shfl_xor(s, off);
  const float invs = 1.f / s;
  float degsum = 0.f;
  for (int t = 0; t < 8; ++t) {
    float bvv = -INFINITY;
    int bii = kSP;
#pragma unroll
    for (int q = 0; q < 5; ++q)
      if (v[q] > bvv) { bvv = v[q]; bii = c[q]; }
    for (int off = 32; off > 0; off >>= 1) {
      float ov = __shfl_xor(bvv, off);
      int oi = __shfl_xor(bii, off);
      if (ov > bvv || (ov == bvv && oi < bii)) { bvv = ov; bii = oi; }
    }
    float p = expf(bvv - m) * invs;
    degsum += p;
    if (lane == 0) { idx8[row * 8 + t] = rowbase + bii; val8[row * 8 + t] = p; }
#pragma unroll
    for (int q = 0; q < 5; ++q)
      if (c[q] == bii) v[q] = -INFINITY;
  }
  if (lane == 0) dinv[row] = 1.f / sqrtf(1.f + degsum);
}

// ------------- GCN aggregation: fp32 Y in; split (+pad zero) or fp32 out -------------
template <int ELU, int OUTF32>
__global__ void gcn_agg(const float* __restrict__ Y, int ldy, int F,
                        const int* __restrict__ idx8, const float* __restrict__ val8,
                        const float* __restrict__ dinv, const float* __restrict__ bias,
                        bf* __restrict__ Zh, bf* __restrict__ Zl,
                        float* __restrict__ Zf, int ldzf) {
  const int n = blockIdx.x;
  __shared__ float w[9];
  __shared__ int srcs[8];
  const int t = threadIdx.x;
  if (t < 8) {
    int s = idx8[n * 8 + t];
    srcs[t] = s;
    w[t] = dinv[n] * val8[n * 8 + t] * dinv[s];
  } else if (t == 8) {
    float di = dinv[n];
    w[8] = di * di;
  }
  __syncthreads();
  const int lim = OUTF32 ? F : ldy;
  for (int f = t * 2; f < lim; f += (int)blockDim.x * 2) {
    size_t on = (size_t)n * ldy + f;
    if (!OUTF32 && f >= F) {
      ushort2v zz = {0, 0};
      *(ushort2v*)((unsigned short*)Zh + on) = zz;
      *(ushort2v*)((unsigned short*)Zl + on) = zz;
      continue;
    }
    floatx2 y0 = *(const floatx2*)(Y + on);
    float a0 = w[8] * y0[0], a1 = w[8] * y0[1];
#pragma unroll
    for (int e = 0; e < 8; ++e) {
      floatx2 ys = *(const floatx2*)(Y + (size_t)srcs[e] * ldy + f);
      a0 += w[e] * ys[0];
      a1 += w[e] * ys[1];
    }
    a0 += bias[f];
    a1 += bias[f + 1];
    if (ELU) {
      a0 = a0 > 0.f ? a0 : expm1f(a0);
      a1 = a1 > 0.f ? a1 : expm1f(a1);
    }
    if (OUTF32) {
      floatx2 o = {a0, a1};
      *(floatx2*)(Zf + (size_t)n * ldzf + f) = o;
    } else {
      bf h0, l0, h1, l1;
      splitf(a0, &h0, &l0);
      splitf(a1, &h1, &l1);
      ushort2v hv = {bfbits(h0), bfbits(h1)};
      ushort2v lv = {bfbits(l0), bfbits(l1)};
      *(ushort2v*)((unsigned short*)Zh + on) = hv;
      *(ushort2v*)((unsigned short*)Zl + on) = lv;
    }
  }
}

}  // namespace

extern "C" void kernel_launch(void* const* d_in, const int* in_sizes, int n_in,
                              void* d_out, int out_size, void* d_ws, size_t ws_size,
                              hipStream_t stream) {
  (void)out_size;

  // ---------- size-keyed role mapping ----------
  const int roleSize[20] = {kB * kS * kD, kD,
                            kD * kARC, kARC, kD * kARC, kARC,
                            kD * kTAG, kTAG, kD * kTAG, kTAG,
                            3 * 501 * 501, 3,
                            kARC * kARC, kARC, kARC * kARC, kARC,
                            kTAG * kTAG, kTAG, kTAG * kTAG, kTAG};
  const int roleOcc[20]  = {0, 0, 0, 0, 1, 1, 0, 0, 1, 1, 0, 0,
                            0, 2, 1, 3, 0, 2, 1, 3};
  int roleIdx[20] = {0, 5, 6, 7, 8, 9, 10, 11, 12, 13, 14, 15,
                     16, 17, 18, 19, 20, 21, 22, 23};
  for (int r = 0; r < 20; ++r) {
    int occ = 0, found = -1;
    for (int i = 0; i < n_in; ++i) {
      if (in_sizes[i] == roleSize[r]) {
        if (occ == roleOcc[r]) { found = i; break; }
        ++occ;
      }
    }
    if (found >= 0) roleIdx[r] = found;
    else if (roleIdx[r] >= n_in) roleIdx[r] = 0;
  }
  const void* src_of[20];
  for (int r = 0; r < 20; ++r) src_of[r] = d_in[roleIdx[r]];

  // ---- workspace layout (function of group batch count GB) ----
  auto need_bytes = [](int GB) -> size_t {
    size_t NG = (size_t)GB * kSP, s = 0;
    auto al = [&](size_t b) { s += (b + 255) & ~(size_t)255; };
    al(256);                                                  // flags
    for (int i = 0; i < 4; ++i) al((size_t)kARC * kD * 2);    // WtHA/DA h,l
    for (int i = 0; i < 4; ++i) al((size_t)kTAG * kD * 2);    // WtHT/DT h,l
    al(kARC * 4); al(kARC * 4); al(kTAG * 4); al(kTAG * 4);   // proj biases
    for (int i = 0; i < 6; ++i) al((size_t)501 * KA * 2);     // bilWt 3 x h,l
    al(3 * 501 * 4); al(256);                                 // brow, bilbf
    for (int i = 0; i < 4; ++i) al((size_t)kARC * KA * 2);    // c1a/c2a h,l
    for (int i = 0; i < 4; ++i) al((size_t)kTAG * KT * 2);    // c1r/c2r h,l
    al(kARC * 4); al(kARC * 4); al(kTAG * 4); al(kTAG * 4);   // conv biases
    al(NG * kD * 2); al(NG * kD * 2);                         // xh, xl
    for (int i = 0; i < 4; ++i) al(NG * KA * 2);              // fHA,fDA h,l
    for (int i = 0; i < 4; ++i) al(NG * KT * 2);              // fHT,fDT h,l
    al(NG * KA * 2); al(NG * KA * 2);                         // Yh, Yl
    al(NG * KA * 4);                                          // Yf (fp32)
    al(NG * kSP * 4);                                         // logits
    al(NG * 8 * 4); al(NG * 8 * 4); al(NG * 4);               // edges
    return s;
  };
  int GB = 1;
  for (int cand : {128, 64, 32, 16, 8, 4, 2, 1})
    if (need_bytes(cand) <= ws_size) { GB = cand; break; }
  const int G = kB / GB;
  const int NG = GB * kSP;
  const int mb = (NG + BM - 1) / BM;

  char* ws = (char*)d_ws;
  size_t off = 0;
  auto alloc = [&](size_t bytes) -> void* {
    void* p = ws + off;
    off += (bytes + 255) & ~(size_t)255;
    return p;
  };
  int* flags = (int*)alloc(256);
  bf *WtHAh = (bf*)alloc((size_t)kARC * kD * 2), *WtHAl = (bf*)alloc((size_t)kARC * kD * 2);
  bf *WtDAh = (bf*)alloc((size_t)kARC * kD * 2), *WtDAl = (bf*)alloc((size_t)kARC * kD * 2);
  bf *WtHTh = (bf*)alloc((size_t)kTAG * kD * 2), *WtHTl = (bf*)alloc((size_t)kTAG * kD * 2);
  bf *WtDTh = (bf*)alloc((size_t)kTAG * kD * 2), *WtDTl = (bf*)alloc((size_t)kTAG * kD * 2);
  float* bha = (float*)alloc(kARC * 4);
  float* bda = (float*)alloc(kARC * 4);
  float* bht = (float*)alloc(kTAG * 4);
  float* bdt = (float*)alloc(kTAG * 4);
  bf* bilWh[3]; bf* bilWl[3];
  for (int k = 0; k < 3; ++k) {
    bilWh[k] = (bf*)alloc((size_t)501 * KA * 2);
    bilWl[k] = (bf*)alloc((size_t)501 * KA * 2);
  }
  float* brow = (float*)alloc(3 * 501 * 4);
  float* bilbf = (float*)alloc(256);
  bf *c1ah = (bf*)alloc((size_t)kARC * KA * 2), *c1al = (bf*)alloc((size_t)kARC * KA * 2);
  bf *c2ah = (bf*)alloc((size_t)kARC * KA * 2), *c2al = (bf*)alloc((size_t)kARC * KA * 2);
  bf *c1rh = (bf*)alloc((size_t)kTAG * KT * 2), *c1rl = (bf*)alloc((size_t)kTAG * KT * 2);
  bf *c2rh = (bf*)alloc((size_t)kTAG * KT * 2), *c2rl = (bf*)alloc((size_t)kTAG * KT * 2);
  float* c1ab = (float*)alloc(kARC * 4);
  float* c2ab = (float*)alloc(kARC * 4);
  float* c1rb = (float*)alloc(kTAG * 4);
  float* c2rb = (float*)alloc(kTAG * 4);
  bf *xh = (bf*)alloc((size_t)NG * kD * 2), *xl = (bf*)alloc((size_t)NG * kD * 2);
  bf *fHAh = (bf*)alloc((size_t)NG * KA * 2), *fHAl = (bf*)alloc((size_t)NG * KA * 2);
  bf *fDAh = (bf*)alloc((size_t)NG * KA * 2), *fDAl = (bf*)alloc((size_t)NG * KA * 2);
  bf *fHTh = (bf*)alloc((size_t)NG * KT * 2), *fHTl = (bf*)alloc((size_t)NG * KT * 2);
  bf *fDTh = (bf*)alloc((size_t)NG * KT * 2), *fDTl = (bf*)alloc((size_t)NG * KT * 2);
  bf *Yh = (bf*)alloc((size_t)NG * KA * 2), *Yl = (bf*)alloc((size_t)NG * KA * 2);
  float* Yf = (float*)alloc((size_t)NG * KA * 4);
  float* logits = (float*)alloc((size_t)NG * kSP * 4);
  int*   idx8 = (int*)alloc((size_t)NG * 8 * 4);
  float* val8 = (float*)alloc((size_t)NG * 8 * 4);
  float* dinv = (float*)alloc((size_t)NG * 4);

  // ---- dtype flags ----
  for (int r = 0; r < 20; ++r) {
    int n = roleSize[r];
    int nwords = n / 4; if (nwords < 1) nwords = 1; if (nwords > 64) nwords = 64;
    detect_dtype_n<<<1, 64, 0, stream>>>((const unsigned*)src_of[r], flags + r, nwords);
  }
  // ---- fp32 biases ----
  auto cvt = [&](int role, float* dst, int n, long o) {
    conv_off<<<(n + 255) / 256, 256, 0, stream>>>(src_of[role], dst, n, o, flags + role);
  };
  cvt(3, bha, kARC, 0); cvt(5, bda, kARC, 0); cvt(7, bht, kTAG, 0); cvt(9, bdt, kTAG, 0);
  cvt(11, bilbf, 3, 0);
  cvt(13, c1ab, kARC, 0); cvt(15, c2ab, kARC, 0); cvt(17, c1rb, kTAG, 0); cvt(19, c2rb, kTAG, 0);
  // ---- transpose+split weights ----
  auto wsp = [&](int role, long o, int ldsrc, int K, int N, int Kpad, bf* Wh, bf* Wl) {
    long tot = (long)N * Kpad;
    wsplit_t<<<(int)((tot + 255) / 256), 256, 0, stream>>>(src_of[role], flags + role, o,
                                                           ldsrc, K, N, Kpad, Wh, Wl);
  };
  wsp(2, 0, kARC, kD, kARC, kD, WtHAh, WtHAl);
  wsp(4, 0, kARC, kD, kARC, kD, WtDAh, WtDAl);
  wsp(6, 0, kTAG, kD, kTAG, kD, WtHTh, WtHTl);
  wsp(8, 0, kTAG, kD, kTAG, kD, WtDTh, WtDTl);
  for (int k = 0; k < 3; ++k) {
    wsp(10, (long)k * 501 * 501, 501, 500, 501, KA, bilWh[k], bilWl[k]);
    cvt(10, brow + k * 501, 501, (long)k * 501 * 501 + 500 * 501);
  }
  wsp(12, 0, kARC, kARC, kARC, KA, c1ah, c1al);
  wsp(14, 0, kARC, kARC, kARC, KA, c2ah, c2al);
  wsp(16, 0, kTAG, kTAG, kTAG, KT, c1rh, c1rl);
  wsp(18, 0, kTAG, kTAG, kTAG, KT, c2rh, c2rl);

  float* outp = (float*)d_out;
  const size_t arc_elems = (size_t)kB * kSP * kSP;

  for (int g = 0; g < G; ++g) {
    const int g0 = g * GB;

    // split x (sentinel-fused) once
    {
      long tot = (long)NG * (kD / 4);
      xsplit<<<(int)((tot + 255) / 256), 256, 0, stream>>>(
          src_of[0], src_of[1], flags + 0, flags + 1, xh, xl, g0, NG);
    }
    // projections: plain split-GEMMs now
    gemm_sp<1, 0><<<dim3(mb, 4), 256, 0, stream>>>(xh, xl, kD, WtHAh, WtHAl, kD,
                                                   fHAh, fHAl, nullptr, KA, NG, kARC, kD, bha);
    gemm_sp<1, 0><<<dim3(mb, 4), 256, 0, stream>>>(xh, xl, kD, WtDAh, WtDAl, kD,
                                                   fDAh, fDAl, nullptr, KA, NG, kARC, kD, bda);
    gemm_sp<1, 0><<<dim3(mb, 1), 256, 0, stream>>>(xh, xl, kD, WtHTh, WtHTl, kD,
                                                   fHTh, fHTl, nullptr, KT, NG, kTAG, kD, bht);
    gemm_sp<1, 0><<<dim3(mb, 1), 256, 0, stream>>>(xh, xl, kD, WtDTh, WtDTl, kD,
                                                   fDTh, fDTl, nullptr, KT, NG, kTAG, kD, bdt);

    for (int k = 0; k < 2; ++k) {
      // T = [fHA|1] @ bilW_k  (N=501, bias = W row 500)
      gemm_sp<2, 0><<<dim3(mb, 4), 256, 0, stream>>>(fHAh, fHAl, KA, bilWh[k], bilWl[k], KA,
                                                     Yh, Yl, nullptr, KA, NG, 501, KA,
                                                     brow + k * 501);
      bilnt_sp<<<dim3(3, 3, GB), 256, 0, stream>>>(Yh, Yl, fDAh, fDAl, logits, bilbf, k, g0, 0);
      softmax_topk<<<NG, 64, 0, stream>>>(logits, idx8, val8, dinv);

      // ARC features
      bf* fh[2] = {fHAh, fDAh};
      bf* fl[2] = {fHAl, fDAl};
      for (int ff = 0; ff < 2; ++ff) {
        gemm_sp<0, 1><<<dim3(mb, 4), 256, 0, stream>>>(fh[ff], fl[ff], KA, c1ah, c1al, KA,
                                                       nullptr, nullptr, Yf, KA, NG, kARC, KA,
                                                       nullptr);
        gcn_agg<1, 0><<<NG, 256, 0, stream>>>(Yf, KA, kARC, idx8, val8, dinv, c1ab,
                                              Yh, Yl, nullptr, 0);
        gemm_sp<0, 1><<<dim3(mb, 4), 256, 0, stream>>>(Yh, Yl, KA, c2ah, c2al, KA,
                                                       nullptr, nullptr, Yf, KA, NG, kARC, KA,
                                                       nullptr);
        gcn_agg<0, 0><<<NG, 256, 0, stream>>>(Yf, KA, kARC, idx8, val8, dinv, c2ab,
                                              fh[ff], fl[ff], nullptr, 0);
      }
      // TAG features
      bf* th[2] = {fHTh, fDTh};
      bf* tl[2] = {fHTl, fDTl};
      for (int ff = 0; ff < 2; ++ff) {
        gemm_sp<0, 1><<<dim3(mb, 1), 256, 0, stream>>>(th[ff], tl[ff], KT, c1rh, c1rl, KT,
                                                       nullptr, nullptr, Yf, KT, NG, kTAG, KT,
                                                       nullptr);
        gcn_agg<1, 0><<<NG, 64, 0, stream>>>(Yf, KT, kTAG, idx8, val8, dinv, c1rb,
                                             Yh, Yl, nullptr, 0);
        gemm_sp<0, 1><<<dim3(mb, 1), 256, 0, stream>>>(Yh, Yl, KT, c2rh, c2rl, KT,
                                                       nullptr, nullptr, Yf, KT, NG, kTAG, KT,
                                                       nullptr);
        if (k == 1) {
          // final tag output -> d_out fp32
          float* dst = outp + arc_elems + (ff == 1 ? (size_t)kN * kTAG : 0)
                       + (size_t)g0 * kSP * kTAG;
          gcn_agg<0, 1><<<NG, 64, 0, stream>>>(Yf, KT, kTAG, idx8, val8, dinv, c2rb,
                                               nullptr, nullptr, dst, kTAG);
        } else {
          gcn_agg<0, 0><<<NG, 64, 0, stream>>>(Yf, KT, kTAG, idx8, val8, dinv, c2rb,
                                               th[ff], tl[ff], nullptr, 0);
        }
      }
    }

    // final bilinear -> d_out fp32
    gemm_sp<2, 0><<<dim3(mb, 4), 256, 0, stream>>>(fHAh, fHAl, KA, bilWh[2], bilWl[2], KA,
                                                   Yh, Yl, nullptr, KA, NG, 501, KA,
                                                   brow + 2 * 501);
    bilnt_sp<<<dim3(3, 3, GB), 256, 0, stream>>>(Yh, Yl, fDAh, fDAl, outp, bilbf, 2, g0, 1);
  }
}

// Round 2
// 3395.128 us; speedup vs baseline: 1.0028x; 1.0028x over previous
//
#include <hip/hip_runtime.h>
#include <hip/hip_bf16.h>
#include <math.h>
#include <cstddef>

namespace {

constexpr int kB   = 128;
constexpr int kS   = 256;
constexpr int kD   = 768;   // multiple of 32
constexpr int kSP  = 257;
constexpr int kN   = kB * kSP;   // 32896 = 257*128
constexpr int kARC = 500;
constexpr int kTAG = 100;
constexpr int KA   = 512;   // padded K for ARC features / T
constexpr int KT   = 128;   // padded K for TAG features

typedef __attribute__((ext_vector_type(8))) short short8;
typedef __attribute__((ext_vector_type(4))) float floatx4;
typedef __attribute__((ext_vector_type(2))) float floatx2;
typedef __attribute__((ext_vector_type(4))) unsigned short ushort4v;
typedef __attribute__((ext_vector_type(2))) unsigned short ushort2v;
typedef __hip_bfloat16 bf;

__device__ __forceinline__ float bfval(bf h) { return __bfloat162float(h); }
__device__ __forceinline__ unsigned short bfbits(bf h) {
  unsigned short u; __builtin_memcpy(&u, &h, 2); return u;
}
__device__ __forceinline__ void splitf(float x, bf* h, bf* l) {
  bf hh = __float2bfloat16(x);
  *h = hh;
  *l = __float2bfloat16(x - __bfloat162float(hh));
}

// async global -> LDS, 16B per lane; LDS dest is wave-uniform base + lane*16
__device__ __forceinline__ void gload16(const bf* g, bf* l) {
  __builtin_amdgcn_global_load_lds(
      (const __attribute__((address_space(1))) void*)g,
      (__attribute__((address_space(3))) void*)l, 16, 0, 0);
}

// ---------- per-tensor dtype detection (1 = bf16 storage, 0 = fp32) ----------
__global__ void detect_dtype_n(const unsigned* __restrict__ raw, int* __restrict__ flag,
                               int nwords) {
  int lane = threadIdx.x;
  int ok = 0, nz = 0;
  if (lane < nwords) {
    unsigned w = raw[lane];
    if (w != 0u) {
      nz = 1;
      int e = (w >> 7) & 0xFF;
      ok = (e >= 90 && e <= 140);
    }
  }
  unsigned long long ball_ok = __ballot(ok);
  unsigned long long ball_nz = __ballot(nz);
  if (lane == 0) {
    int cok = __popcll(ball_ok), cnz = __popcll(ball_nz);
    flag[0] = (cok * 4 >= cnz * 3) ? 1 : 0;
  }
}

__device__ __forceinline__ float rawload(const void* p, size_t i, int bfm) {
  return bfm ? __bfloat162float(((const bf*)p)[i]) : ((const float*)p)[i];
}

// fp32 canonicalize with element offset
__global__ void conv_off(const void* __restrict__ src, float* __restrict__ dst,
                         int n, long off, const int* __restrict__ flag) {
  int i = blockIdx.x * 256 + threadIdx.x;
  if (i >= n) return;
  dst[i] = rawload(src, (size_t)off + i, *flag);
}

// transpose + split weight: raw W[K][N] (row stride ldsrc) -> Wh/Wl [N][Kpad], zero pad
__global__ void wsplit_t(const void* __restrict__ src, const int* __restrict__ flag,
                         long srcOff, int ldsrc, int K, int N, int Kpad,
                         bf* __restrict__ Wh, bf* __restrict__ Wl) {
  long idx = (long)blockIdx.x * 256 + threadIdx.x;
  if (idx >= (long)N * Kpad) return;
  int n = (int)(idx / Kpad), k = (int)(idx % Kpad);
  float v = (k < K) ? rawload(src, (size_t)srcOff + (size_t)k * ldsrc + n, *flag) : 0.f;
  bf h, l;
  splitf(v, &h, &l);
  Wh[idx] = h; Wl[idx] = l;
}

// ---------- x split: sentinel-fused input -> xh/xl [NG][768] ----------
__global__ void xsplit(const void* __restrict__ inp, const void* __restrict__ sent,
                       const int* __restrict__ fi, const int* __restrict__ fs,
                       bf* __restrict__ xh, bf* __restrict__ xl, int g0, int NG) {
  long idx = (long)blockIdx.x * 256 + threadIdx.x;   // one quad of elements
  long tot = (long)NG * (kD / 4);
  if (idx >= tot) return;
  int n = (int)(idx / (kD / 4));
  int k = (int)(idx % (kD / 4)) * 4;
  int b = n / kSP, r = n - b * kSP;
  const void* src;
  size_t base;
  int bfm;
  if (r == 0) { src = sent; base = (size_t)k; bfm = *fs; }
  else {
    src = inp;
    base = ((size_t)((g0 + b) * kS + (r - 1))) * kD + k;
    bfm = *fi;
  }
  float v[4];
  if (bfm) {
    ushort4v s = *(const ushort4v*)((const unsigned short*)src + base);
#pragma unroll
    for (int j = 0; j < 4; ++j) {
      bf h; unsigned short u = s[j];
      __builtin_memcpy(&h, &u, 2);
      v[j] = __bfloat162float(h);
    }
  } else {
    floatx4 f4 = *(const floatx4*)((const float*)src + base);
#pragma unroll
    for (int j = 0; j < 4; ++j) v[j] = f4[j];
  }
  ushort4v h4, l4;
#pragma unroll
  for (int j = 0; j < 4; ++j) {
    bf h, l;
    splitf(v[j], &h, &l);
    h4[j] = bfbits(h); l4[j] = bfbits(l);
  }
  size_t o = (size_t)n * kD + k;
  *(ushort4v*)((unsigned short*)xh + o) = h4;
  *(ushort4v*)((unsigned short*)xl + o) = l4;
}

// =================== split-bf16 MFMA GEMM, dbuf global_load_lds staging ===================
// C[M,N] = act( sum_k (Ah+Al)[m,k]*(Bh+Bl)[n,k] + bias[n]? )  (drop lo*lo)
// EPI: 0 none, 1 bias+elu, 2 bias.  OUTF32: 1 -> Cf fp32 (no pad writes),
//                                   0 -> split planes Ch/Cl with [N,ldc) zeroed.
// Schedule: 2-phase double-buffer — prefetch tile t+1 issued BEFORE compute of tile t,
// one __syncthreads per K-step (its vmcnt(0) drain lands after ds_read+MFMA work).
constexpr int BM = 128, BN = 128, BK = 32;

template <int EPI, int OUTF32>
__global__ __launch_bounds__(256) void gemm_sp(
    const bf* __restrict__ Ah, const bf* __restrict__ Al, int lda,
    const bf* __restrict__ Bh, const bf* __restrict__ Bl, int ldb,
    bf* __restrict__ Ch, bf* __restrict__ Cl, float* __restrict__ Cf, int ldc,
    int M, int N, int K, const float* __restrict__ bias) {
  __shared__ bf sAh[2][BM][BK];
  __shared__ bf sAl[2][BM][BK];
  __shared__ bf sBh[2][BN][BK];
  __shared__ bf sBl[2][BN][BK];
  const int tid = threadIdx.x;
  const int lane = tid & 63, wave = tid >> 6;
  const int quad = lane >> 4, l15 = lane & 15;
  const int wm = (wave >> 1) * 64, wn = (wave & 1) * 64;
  const int m0 = blockIdx.x * BM, n0 = blockIdx.y * BN;
  const int lrow = lane >> 2, lkof = (lane & 3) * 8;

  // per-lane global bases (row-clamped; garbage lands only in discarded C rows/cols)
  const bf *pAh[2], *pAl[2], *pBh[2], *pBl[2];
  int rb[2];
#pragma unroll
  for (int jj = 0; jj < 2; ++jj) {
    rb[jj] = wave * 32 + jj * 16;
    int gm = m0 + rb[jj] + lrow; if (gm > M - 1) gm = M - 1;
    int gn = n0 + rb[jj] + lrow; if (gn > N - 1) gn = N - 1;
    pAh[jj] = Ah + (size_t)gm * lda + lkof;
    pAl[jj] = Al + (size_t)gm * lda + lkof;
    pBh[jj] = Bh + (size_t)gn * ldb + lkof;
    pBl[jj] = Bl + (size_t)gn * ldb + lkof;
  }

  auto stage = [&](int bi, int k0) {
#pragma unroll
    for (int jj = 0; jj < 2; ++jj) {
      gload16(pAh[jj] + k0, &sAh[bi][rb[jj]][0]);
      gload16(pAl[jj] + k0, &sAl[bi][rb[jj]][0]);
      gload16(pBh[jj] + k0, &sBh[bi][rb[jj]][0]);
      gload16(pBl[jj] + k0, &sBl[bi][rb[jj]][0]);
    }
  };

  floatx4 acc[4][4] = {};
  stage(0, 0);
  int cur = 0;
  for (int k0 = 0; k0 < K; k0 += BK) {
    __syncthreads();                    // drains vmcnt -> buf[cur] staged & prior reads done
    if (k0 + BK < K) stage(cur ^ 1, k0 + BK);   // prefetch flies during ds_read+MFMA
    short8 a_h[4], a_l[4], b_h[4], b_l[4];
#pragma unroll
    for (int t = 0; t < 4; ++t) {
      a_h[t] = *(const short8*)&sAh[cur][wm + t * 16 + l15][quad * 8];
      a_l[t] = *(const short8*)&sAl[cur][wm + t * 16 + l15][quad * 8];
      b_h[t] = *(const short8*)&sBh[cur][wn + t * 16 + l15][quad * 8];
      b_l[t] = *(const short8*)&sBl[cur][wn + t * 16 + l15][quad * 8];
    }
#pragma unroll
    for (int mt = 0; mt < 4; ++mt)
#pragma unroll
      for (int nt = 0; nt < 4; ++nt) {
        acc[mt][nt] = __builtin_amdgcn_mfma_f32_16x16x32_bf16(a_h[mt], b_h[nt], acc[mt][nt], 0, 0, 0);
        acc[mt][nt] = __builtin_amdgcn_mfma_f32_16x16x32_bf16(a_h[mt], b_l[nt], acc[mt][nt], 0, 0, 0);
        acc[mt][nt] = __builtin_amdgcn_mfma_f32_16x16x32_bf16(a_l[mt], b_h[nt], acc[mt][nt], 0, 0, 0);
      }
    cur ^= 1;
  }
#pragma unroll
  for (int mt = 0; mt < 4; ++mt)
#pragma unroll
    for (int reg = 0; reg < 4; ++reg) {
      int m = m0 + wm + mt * 16 + quad * 4 + reg;
      if (m >= M) continue;
#pragma unroll
      for (int nt = 0; nt < 4; ++nt) {
        int n = n0 + wn + nt * 16 + l15;
        if (OUTF32) {
          if (n < N) {
            float v = acc[mt][nt][reg];
            if (EPI >= 1) v += bias[n];
            if (EPI == 1) v = v > 0.f ? v : expm1f(v);
            Cf[(size_t)m * ldc + n] = v;
          }
        } else {
          size_t o = (size_t)m * ldc + n;
          if (n < N) {
            float v = acc[mt][nt][reg];
            if (EPI >= 1) v += bias[n];
            if (EPI == 1) v = v > 0.f ? v : expm1f(v);
            bf h, l;
            splitf(v, &h, &l);
            Ch[o] = h; Cl[o] = l;
          } else if (n < ldc) {
            Ch[o] = __float2bfloat16(0.f);
            Cl[o] = __float2bfloat16(0.f);
          }
        }
      }
    }
}

// ====== batched NT bilinear, dbuf global_load_lds staging; out fp32 +rowterm +bilb ======
__global__ __launch_bounds__(256) void bilnt_sp(
    const bf* __restrict__ Th, const bf* __restrict__ Tl,  // [GB*257][512]
    const bf* __restrict__ Fh, const bf* __restrict__ Fl,  // featDA
    float* __restrict__ out, const float* __restrict__ bilb, int bidx,
    int g0, int globOut) {
  __shared__ bf sAh[2][BM][BK];
  __shared__ bf sAl[2][BM][BK];
  __shared__ bf sBh[2][BN][BK];
  __shared__ bf sBl[2][BN][BK];
  const int z = blockIdx.z;
  const int tid = threadIdx.x;
  const int lane = tid & 63, wave = tid >> 6;
  const int quad = lane >> 4, l15 = lane & 15;
  const int wm = (wave >> 1) * 64, wn = (wave & 1) * 64;
  const int m0 = blockIdx.x * BM, n0 = blockIdx.y * BN;
  const int lrow = lane >> 2, lkof = (lane & 3) * 8;
  const bf* Ah = Th + (size_t)z * kSP * KA;
  const bf* Al = Tl + (size_t)z * kSP * KA;
  const bf* Bh = Fh + (size_t)z * kSP * KA;
  const bf* Bl = Fl + (size_t)z * kSP * KA;

  const bf *pAh[2], *pAl[2], *pBh[2], *pBl[2];
  int rb[2];
#pragma unroll
  for (int jj = 0; jj < 2; ++jj) {
    rb[jj] = wave * 32 + jj * 16;
    int gm = m0 + rb[jj] + lrow; if (gm > kSP - 1) gm = kSP - 1;
    int gn = n0 + rb[jj] + lrow; if (gn > kSP - 1) gn = kSP - 1;
    pAh[jj] = Ah + (size_t)gm * KA + lkof;
    pAl[jj] = Al + (size_t)gm * KA + lkof;
    pBh[jj] = Bh + (size_t)gn * KA + lkof;
    pBl[jj] = Bl + (size_t)gn * KA + lkof;
  }

  auto stage = [&](int bi, int k0) {
#pragma unroll
    for (int jj = 0; jj < 2; ++jj) {
      gload16(pAh[jj] + k0, &sAh[bi][rb[jj]][0]);
      gload16(pAl[jj] + k0, &sAl[bi][rb[jj]][0]);
      gload16(pBh[jj] + k0, &sBh[bi][rb[jj]][0]);
      gload16(pBl[jj] + k0, &sBl[bi][rb[jj]][0]);
    }
  };

  floatx4 acc[4][4] = {};
  stage(0, 0);
  int cur = 0;
  for (int k0 = 0; k0 < KA; k0 += BK) {
    __syncthreads();
    if (k0 + BK < KA) stage(cur ^ 1, k0 + BK);
    short8 a_h[4], a_l[4], b_h[4], b_l[4];
#pragma unroll
    for (int t = 0; t < 4; ++t) {
      a_h[t] = *(const short8*)&sAh[cur][wm + t * 16 + l15][quad * 8];
      a_l[t] = *(const short8*)&sAl[cur][wm + t * 16 + l15][quad * 8];
      b_h[t] = *(const short8*)&sBh[cur][wn + t * 16 + l15][quad * 8];
      b_l[t] = *(const short8*)&sBl[cur][wn + t * 16 + l15][quad * 8];
    }
#pragma unroll
    for (int mt = 0; mt < 4; ++mt)
#pragma unroll
      for (int nt = 0; nt < 4; ++nt) {
        acc[mt][nt] = __builtin_amdgcn_mfma_f32_16x16x32_bf16(a_h[mt], b_h[nt], acc[mt][nt], 0, 0, 0);
        acc[mt][nt] = __builtin_amdgcn_mfma_f32_16x16x32_bf16(a_h[mt], b_l[nt], acc[mt][nt], 0, 0, 0);
        acc[mt][nt] = __builtin_amdgcn_mfma_f32_16x16x32_bf16(a_l[mt], b_h[nt], acc[mt][nt], 0, 0, 0);
      }
    cur ^= 1;
  }
  const float sb = bilb[bidx];
  const int bb = globOut ? (g0 + z) : z;
#pragma unroll
  for (int mt = 0; mt < 4; ++mt)
#pragma unroll
    for (int reg = 0; reg < 4; ++reg) {
      int i = m0 + wm + mt * 16 + quad * 4 + reg;
      if (i >= kSP) continue;
      float rowterm = bfval(Ah[(size_t)i * KA + 500]) + bfval(Al[(size_t)i * KA + 500]) + sb;
#pragma unroll
      for (int nt = 0; nt < 4; ++nt) {
        int j = n0 + wn + nt * 16 + l15;
        if (j >= kSP) continue;
        out[((size_t)bb * kSP + i) * kSP + j] = acc[mt][nt][reg] + rowterm;
      }
    }
}

// ------------- per-row softmax + top-8 (+dinv); one wave per row -------------
__global__ void softmax_topk(const float* __restrict__ logits,
                             int* __restrict__ idx8,
                             float* __restrict__ val8,
                             float* __restrict__ dinv) {
  const int row = blockIdx.x;
  const int lane = threadIdx.x;
  const int rowbase = row - (row % kSP);
  const float* L = logits + (size_t)row * kSP;
  float v[5];
  int c[5];
#pragma unroll
  for (int q = 0; q < 5; ++q) {
    int j = lane + q * 64;
    c[q] = j;
    v[q] = (j < kSP) ? L[j] : -INFINITY;
  }
  float m = v[0];
#pragma unroll
  for (int q = 1; q < 5; ++q) m = fmaxf(m, v[q]);
  for (int off = 32; off > 0; off >>= 1) m = fmaxf(m, __shfl_xor(m, off));
  float s = 0.f;
#pragma unroll
  for (int q = 0; q < 5; ++q) s += expf(v[q] - m);
  for (int off = 32; off > 0; off >>= 1) s += __shfl_xor(s, off);
  const float invs = 1.f / s;
  float degsum = 0.f;
  for (int t = 0; t < 8; ++t) {
    float bvv = -INFINITY;
    int bii = kSP;
#pragma unroll
    for (int q = 0; q < 5; ++q)
      if (v[q] > bvv) { bvv = v[q]; bii = c[q]; }
    for (int off = 32; off > 0; off >>= 1) {
      float ov = __shfl_xor(bvv, off);
      int oi = __shfl_xor(bii, off);
      if (ov > bvv || (ov == bvv && oi < bii)) { bvv = ov; bii = oi; }
    }
    float p = expf(bvv - m) * invs;
    degsum += p;
    if (lane == 0) { idx8[row * 8 + t] = rowbase + bii; val8[row * 8 + t] = p; }
#pragma unroll
    for (int q = 0; q < 5; ++q)
      if (c[q] == bii) v[q] = -INFINITY;
  }
  if (lane == 0) dinv[row] = 1.f / sqrtf(1.f + degsum);
}

// ------------- GCN aggregation: fp32 Y in; split (+pad zero) or fp32 out -------------
template <int ELU, int OUTF32>
__global__ void gcn_agg(const float* __restrict__ Y, int ldy, int F,
                        const int* __restrict__ idx8, const float* __restrict__ val8,
                        const float* __restrict__ dinv, const float* __restrict__ bias,
                        bf* __restrict__ Zh, bf* __restrict__ Zl,
                        float* __restrict__ Zf, int ldzf) {
  const int n = blockIdx.x;
  __shared__ float w[9];
  __shared__ int srcs[8];
  const int t = threadIdx.x;
  if (t < 8) {
    int s = idx8[n * 8 + t];
    srcs[t] = s;
    w[t] = dinv[n] * val8[n * 8 + t] * dinv[s];
  } else if (t == 8) {
    float di = dinv[n];
    w[8] = di * di;
  }
  __syncthreads();
  const int lim = OUTF32 ? F : ldy;
  for (int f = t * 2; f < lim; f += (int)blockDim.x * 2) {
    size_t on = (size_t)n * ldy + f;
    if (!OUTF32 && f >= F) {
      ushort2v zz = {0, 0};
      *(ushort2v*)((unsigned short*)Zh + on) = zz;
      *(ushort2v*)((unsigned short*)Zl + on) = zz;
      continue;
    }
    floatx2 y0 = *(const floatx2*)(Y + on);
    float a0 = w[8] * y0[0], a1 = w[8] * y0[1];
#pragma unroll
    for (int e = 0; e < 8; ++e) {
      floatx2 ys = *(const floatx2*)(Y + (size_t)srcs[e] * ldy + f);
      a0 += w[e] * ys[0];
      a1 += w[e] * ys[1];
    }
    a0 += bias[f];
    a1 += bias[f + 1];
    if (ELU) {
      a0 = a0 > 0.f ? a0 : expm1f(a0);
      a1 = a1 > 0.f ? a1 : expm1f(a1);
    }
    if (OUTF32) {
      floatx2 o = {a0, a1};
      *(floatx2*)(Zf + (size_t)n * ldzf + f) = o;
    } else {
      bf h0, l0, h1, l1;
      splitf(a0, &h0, &l0);
      splitf(a1, &h1, &l1);
      ushort2v hv = {bfbits(h0), bfbits(h1)};
      ushort2v lv = {bfbits(l0), bfbits(l1)};
      *(ushort2v*)((unsigned short*)Zh + on) = hv;
      *(ushort2v*)((unsigned short*)Zl + on) = lv;
    }
  }
}

}  // namespace

extern "C" void kernel_launch(void* const* d_in, const int* in_sizes, int n_in,
                              void* d_out, int out_size, void* d_ws, size_t ws_size,
                              hipStream_t stream) {
  (void)out_size;

  // ---------- size-keyed role mapping ----------
  const int roleSize[20] = {kB * kS * kD, kD,
                            kD * kARC, kARC, kD * kARC, kARC,
                            kD * kTAG, kTAG, kD * kTAG, kTAG,
                            3 * 501 * 501, 3,
                            kARC * kARC, kARC, kARC * kARC, kARC,
                            kTAG * kTAG, kTAG, kTAG * kTAG, kTAG};
  const int roleOcc[20]  = {0, 0, 0, 0, 1, 1, 0, 0, 1, 1, 0, 0,
                            0, 2, 1, 3, 0, 2, 1, 3};
  int roleIdx[20] = {0, 5, 6, 7, 8, 9, 10, 11, 12, 13, 14, 15,
                     16, 17, 18, 19, 20, 21, 22, 23};
  for (int r = 0; r < 20; ++r) {
    int occ = 0, found = -1;
    for (int i = 0; i < n_in; ++i) {
      if (in_sizes[i] == roleSize[r]) {
        if (occ == roleOcc[r]) { found = i; break; }
        ++occ;
      }
    }
    if (found >= 0) roleIdx[r] = found;
    else if (roleIdx[r] >= n_in) roleIdx[r] = 0;
  }
  const void* src_of[20];
  for (int r = 0; r < 20; ++r) src_of[r] = d_in[roleIdx[r]];

  // ---- workspace layout (function of group batch count GB) ----
  auto need_bytes = [](int GB) -> size_t {
    size_t NG = (size_t)GB * kSP, s = 0;
    auto al = [&](size_t b) { s += (b + 255) & ~(size_t)255; };
    al(256);                                                  // flags
    for (int i = 0; i < 4; ++i) al((size_t)kARC * kD * 2);    // WtHA/DA h,l
    for (int i = 0; i < 4; ++i) al((size_t)kTAG * kD * 2);    // WtHT/DT h,l
    al(kARC * 4); al(kARC * 4); al(kTAG * 4); al(kTAG * 4);   // proj biases
    for (int i = 0; i < 6; ++i) al((size_t)501 * KA * 2);     // bilWt 3 x h,l
    al(3 * 501 * 4); al(256);                                 // brow, bilbf
    for (int i = 0; i < 4; ++i) al((size_t)kARC * KA * 2);    // c1a/c2a h,l
    for (int i = 0; i < 4; ++i) al((size_t)kTAG * KT * 2);    // c1r/c2r h,l
    al(kARC * 4); al(kARC * 4); al(kTAG * 4); al(kTAG * 4);   // conv biases
    al(NG * kD * 2); al(NG * kD * 2);                         // xh, xl
    for (int i = 0; i < 4; ++i) al(NG * KA * 2);              // fHA,fDA h,l
    for (int i = 0; i < 4; ++i) al(NG * KT * 2);              // fHT,fDT h,l
    al(NG * KA * 2); al(NG * KA * 2);                         // Yh, Yl
    al(NG * KA * 4);                                          // Yf (fp32)
    al(NG * kSP * 4);                                         // logits
    al(NG * 8 * 4); al(NG * 8 * 4); al(NG * 4);               // edges
    return s;
  };
  int GB = 1;
  for (int cand : {128, 64, 32, 16, 8, 4, 2, 1})
    if (need_bytes(cand) <= ws_size) { GB = cand; break; }
  const int G = kB / GB;
  const int NG = GB * kSP;
  const int mb = (NG + BM - 1) / BM;

  char* ws = (char*)d_ws;
  size_t off = 0;
  auto alloc = [&](size_t bytes) -> void* {
    void* p = ws + off;
    off += (bytes + 255) & ~(size_t)255;
    return p;
  };
  int* flags = (int*)alloc(256);
  bf *WtHAh = (bf*)alloc((size_t)kARC * kD * 2), *WtHAl = (bf*)alloc((size_t)kARC * kD * 2);
  bf *WtDAh = (bf*)alloc((size_t)kARC * kD * 2), *WtDAl = (bf*)alloc((size_t)kARC * kD * 2);
  bf *WtHTh = (bf*)alloc((size_t)kTAG * kD * 2), *WtHTl = (bf*)alloc((size_t)kTAG * kD * 2);
  bf *WtDTh = (bf*)alloc((size_t)kTAG * kD * 2), *WtDTl = (bf*)alloc((size_t)kTAG * kD * 2);
  float* bha = (float*)alloc(kARC * 4);
  float* bda = (float*)alloc(kARC * 4);
  float* bht = (float*)alloc(kTAG * 4);
  float* bdt = (float*)alloc(kTAG * 4);
  bf* bilWh[3]; bf* bilWl[3];
  for (int k = 0; k < 3; ++k) {
    bilWh[k] = (bf*)alloc((size_t)501 * KA * 2);
    bilWl[k] = (bf*)alloc((size_t)501 * KA * 2);
  }
  float* brow = (float*)alloc(3 * 501 * 4);
  float* bilbf = (float*)alloc(256);
  bf *c1ah = (bf*)alloc((size_t)kARC * KA * 2), *c1al = (bf*)alloc((size_t)kARC * KA * 2);
  bf *c2ah = (bf*)alloc((size_t)kARC * KA * 2), *c2al = (bf*)alloc((size_t)kARC * KA * 2);
  bf *c1rh = (bf*)alloc((size_t)kTAG * KT * 2), *c1rl = (bf*)alloc((size_t)kTAG * KT * 2);
  bf *c2rh = (bf*)alloc((size_t)kTAG * KT * 2), *c2rl = (bf*)alloc((size_t)kTAG * KT * 2);
  float* c1ab = (float*)alloc(kARC * 4);
  float* c2ab = (float*)alloc(kARC * 4);
  float* c1rb = (float*)alloc(kTAG * 4);
  float* c2rb = (float*)alloc(kTAG * 4);
  bf *xh = (bf*)alloc((size_t)NG * kD * 2), *xl = (bf*)alloc((size_t)NG * kD * 2);
  bf *fHAh = (bf*)alloc((size_t)NG * KA * 2), *fHAl = (bf*)alloc((size_t)NG * KA * 2);
  bf *fDAh = (bf*)alloc((size_t)NG * KA * 2), *fDAl = (bf*)alloc((size_t)NG * KA * 2);
  bf *fHTh = (bf*)alloc((size_t)NG * KT * 2), *fHTl = (bf*)alloc((size_t)NG * KT * 2);
  bf *fDTh = (bf*)alloc((size_t)NG * KT * 2), *fDTl = (bf*)alloc((size_t)NG * KT * 2);
  bf *Yh = (bf*)alloc((size_t)NG * KA * 2), *Yl = (bf*)alloc((size_t)NG * KA * 2);
  float* Yf = (float*)alloc((size_t)NG * KA * 4);
  float* logits = (float*)alloc((size_t)NG * kSP * 4);
  int*   idx8 = (int*)alloc((size_t)NG * 8 * 4);
  float* val8 = (float*)alloc((size_t)NG * 8 * 4);
  float* dinv = (float*)alloc((size_t)NG * 4);

  // ---- dtype flags ----
  for (int r = 0; r < 20; ++r) {
    int n = roleSize[r];
    int nwords = n / 4; if (nwords < 1) nwords = 1; if (nwords > 64) nwords = 64;
    detect_dtype_n<<<1, 64, 0, stream>>>((const unsigned*)src_of[r], flags + r, nwords);
  }
  // ---- fp32 biases ----
  auto cvt = [&](int role, float* dst, int n, long o) {
    conv_off<<<(n + 255) / 256, 256, 0, stream>>>(src_of[role], dst, n, o, flags + role);
  };
  cvt(3, bha, kARC, 0); cvt(5, bda, kARC, 0); cvt(7, bht, kTAG, 0); cvt(9, bdt, kTAG, 0);
  cvt(11, bilbf, 3, 0);
  cvt(13, c1ab, kARC, 0); cvt(15, c2ab, kARC, 0); cvt(17, c1rb, kTAG, 0); cvt(19, c2rb, kTAG, 0);
  // ---- transpose+split weights ----
  auto wsp = [&](int role, long o, int ldsrc, int K, int N, int Kpad, bf* Wh, bf* Wl) {
    long tot = (long)N * Kpad;
    wsplit_t<<<(int)((tot + 255) / 256), 256, 0, stream>>>(src_of[role], flags + role, o,
                                                           ldsrc, K, N, Kpad, Wh, Wl);
  };
  wsp(2, 0, kARC, kD, kARC, kD, WtHAh, WtHAl);
  wsp(4, 0, kARC, kD, kARC, kD, WtDAh, WtDAl);
  wsp(6, 0, kTAG, kD, kTAG, kD, WtHTh, WtHTl);
  wsp(8, 0, kTAG, kD, kTAG, kD, WtDTh, WtDTl);
  for (int k = 0; k < 3; ++k) {
    wsp(10, (long)k * 501 * 501, 501, 500, 501, KA, bilWh[k], bilWl[k]);
    cvt(10, brow + k * 501, 501, (long)k * 501 * 501 + 500 * 501);
  }
  wsp(12, 0, kARC, kARC, kARC, KA, c1ah, c1al);
  wsp(14, 0, kARC, kARC, kARC, KA, c2ah, c2al);
  wsp(16, 0, kTAG, kTAG, kTAG, KT, c1rh, c1rl);
  wsp(18, 0, kTAG, kTAG, kTAG, KT, c2rh, c2rl);

  float* outp = (float*)d_out;
  const size_t arc_elems = (size_t)kB * kSP * kSP;

  for (int g = 0; g < G; ++g) {
    const int g0 = g * GB;

    // split x (sentinel-fused) once
    {
      long tot = (long)NG * (kD / 4);
      xsplit<<<(int)((tot + 255) / 256), 256, 0, stream>>>(
          src_of[0], src_of[1], flags + 0, flags + 1, xh, xl, g0, NG);
    }
    // projections: plain split-GEMMs now
    gemm_sp<1, 0><<<dim3(mb, 4), 256, 0, stream>>>(xh, xl, kD, WtHAh, WtHAl, kD,
                                                   fHAh, fHAl, nullptr, KA, NG, kARC, kD, bha);
    gemm_sp<1, 0><<<dim3(mb, 4), 256, 0, stream>>>(xh, xl, kD, WtDAh, WtDAl, kD,
                                                   fDAh, fDAl, nullptr, KA, NG, kARC, kD, bda);
    gemm_sp<1, 0><<<dim3(mb, 1), 256, 0, stream>>>(xh, xl, kD, WtHTh, WtHTl, kD,
                                                   fHTh, fHTl, nullptr, KT, NG, kTAG, kD, bht);
    gemm_sp<1, 0><<<dim3(mb, 1), 256, 0, stream>>>(xh, xl, kD, WtDTh, WtDTl, kD,
                                                   fDTh, fDTl, nullptr, KT, NG, kTAG, kD, bdt);

    for (int k = 0; k < 2; ++k) {
      // T = [fHA|1] @ bilW_k  (N=501, bias = W row 500)
      gemm_sp<2, 0><<<dim3(mb, 4), 256, 0, stream>>>(fHAh, fHAl, KA, bilWh[k], bilWl[k], KA,
                                                     Yh, Yl, nullptr, KA, NG, 501, KA,
                                                     brow + k * 501);
      bilnt_sp<<<dim3(3, 3, GB), 256, 0, stream>>>(Yh, Yl, fDAh, fDAl, logits, bilbf, k, g0, 0);
      softmax_topk<<<NG, 64, 0, stream>>>(logits, idx8, val8, dinv);

      // ARC features
      bf* fh[2] = {fHAh, fDAh};
      bf* fl[2] = {fHAl, fDAl};
      for (int ff = 0; ff < 2; ++ff) {
        gemm_sp<0, 1><<<dim3(mb, 4), 256, 0, stream>>>(fh[ff], fl[ff], KA, c1ah, c1al, KA,
                                                       nullptr, nullptr, Yf, KA, NG, kARC, KA,
                                                       nullptr);
        gcn_agg<1, 0><<<NG, 256, 0, stream>>>(Yf, KA, kARC, idx8, val8, dinv, c1ab,
                                              Yh, Yl, nullptr, 0);
        gemm_sp<0, 1><<<dim3(mb, 4), 256, 0, stream>>>(Yh, Yl, KA, c2ah, c2al, KA,
                                                       nullptr, nullptr, Yf, KA, NG, kARC, KA,
                                                       nullptr);
        gcn_agg<0, 0><<<NG, 256, 0, stream>>>(Yf, KA, kARC, idx8, val8, dinv, c2ab,
                                              fh[ff], fl[ff], nullptr, 0);
      }
      // TAG features
      bf* th[2] = {fHTh, fDTh};
      bf* tl[2] = {fHTl, fDTl};
      for (int ff = 0; ff < 2; ++ff) {
        gemm_sp<0, 1><<<dim3(mb, 1), 256, 0, stream>>>(th[ff], tl[ff], KT, c1rh, c1rl, KT,
                                                       nullptr, nullptr, Yf, KT, NG, kTAG, KT,
                                                       nullptr);
        gcn_agg<1, 0><<<NG, 64, 0, stream>>>(Yf, KT, kTAG, idx8, val8, dinv, c1rb,
                                             Yh, Yl, nullptr, 0);
        gemm_sp<0, 1><<<dim3(mb, 1), 256, 0, stream>>>(Yh, Yl, KT, c2rh, c2rl, KT,
                                                       nullptr, nullptr, Yf, KT, NG, kTAG, KT,
                                                       nullptr);
        if (k == 1) {
          // final tag output -> d_out fp32
          float* dst = outp + arc_elems + (ff == 1 ? (size_t)kN * kTAG : 0)
                       + (size_t)g0 * kSP * kTAG;
          gcn_agg<0, 1><<<NG, 64, 0, stream>>>(Yf, KT, kTAG, idx8, val8, dinv, c2rb,
                                               nullptr, nullptr, dst, kTAG);
        } else {
          gcn_agg<0, 0><<<NG, 64, 0, stream>>>(Yf, KT, kTAG, idx8, val8, dinv, c2rb,
                                               th[ff], tl[ff], nullptr, 0);
        }
      }
    }

    // final bilinear -> d_out fp32
    gemm_sp<2, 0><<<dim3(mb, 4), 256, 0, stream>>>(fHAh, fHAl, KA, bilWh[2], bilWl[2], KA,
                                                   Yh, Yl, nullptr, KA, NG, 501, KA,
                                                   brow + 2 * 501);
    bilnt_sp<<<dim3(3, 3, GB), 256, 0, stream>>>(Yh, Yl, fDAh, fDAl, outp, bilbf, 2, g0, 1);
  }
}

// Round 3
// 2797.672 us; speedup vs baseline: 1.2169x; 1.2136x over previous
//
#include <hip/hip_runtime.h>
#include <hip/hip_bf16.h>
#include <math.h>
#include <cstddef>

namespace {

constexpr int kB   = 128;
constexpr int kS   = 256;
constexpr int kD   = 768;
constexpr int kSP  = 257;
constexpr int kN   = kB * kSP;
constexpr int kARC = 500;
constexpr int kTAG = 100;
constexpr int KA   = 512;   // padded ARC feature width
constexpr int KT   = 128;   // padded TAG feature width
constexpr int NPA  = 1024;  // concat ARC proj width (512+512)
constexpr int NPT  = 256;   // concat TAG proj width (128+128)

typedef __attribute__((ext_vector_type(8))) short short8;
typedef __attribute__((ext_vector_type(4))) float floatx4;
typedef __attribute__((ext_vector_type(2))) float floatx2;
typedef __attribute__((ext_vector_type(4))) unsigned short ushort4v;
typedef __attribute__((ext_vector_type(2))) unsigned short ushort2v;
typedef __hip_bfloat16 bf;

__device__ __forceinline__ float bfval(bf h) { return __bfloat162float(h); }
__device__ __forceinline__ unsigned short bfbits(bf h) {
  unsigned short u; __builtin_memcpy(&u, &h, 2); return u;
}
__device__ __forceinline__ void splitf(float x, bf* h, bf* l) {
  bf hh = __float2bfloat16(x);
  *h = hh;
  *l = __float2bfloat16(x - __bfloat162float(hh));
}

// bijective XCD chunking (m204): contiguous swz ranges land on one XCD
__device__ __forceinline__ int swz8(int lid, int total) {
  int q = total >> 3, r = total & 7;
  int c = lid & 7, p = lid >> 3;
  return (c < r ? c * (q + 1) : r * (q + 1) + (c - r) * q) + p;
}

// async global -> LDS, 16B per lane; LDS dest is wave-uniform base + lane*16
__device__ __forceinline__ void gload16(const bf* g, bf* l) {
  __builtin_amdgcn_global_load_lds(
      (const __attribute__((address_space(1))) void*)g,
      (__attribute__((address_space(3))) void*)l, 16, 0, 0);
}

__global__ void zerofill(unsigned* __restrict__ p, long n4) {
  long i = (long)blockIdx.x * 256 + threadIdx.x;
  if (i < n4) p[i] = 0u;
}

// ---------- per-tensor dtype detection (1 = bf16 storage, 0 = fp32) ----------
__global__ void detect_dtype_n(const unsigned* __restrict__ raw, int* __restrict__ flag,
                               int nwords) {
  int lane = threadIdx.x;
  int ok = 0, nz = 0;
  if (lane < nwords) {
    unsigned w = raw[lane];
    if (w != 0u) {
      nz = 1;
      int e = (w >> 7) & 0xFF;
      ok = (e >= 90 && e <= 140);
    }
  }
  unsigned long long ball_ok = __ballot(ok);
  unsigned long long ball_nz = __ballot(nz);
  if (lane == 0) {
    int cok = __popcll(ball_ok), cnz = __popcll(ball_nz);
    flag[0] = (cok * 4 >= cnz * 3) ? 1 : 0;
  }
}

__device__ __forceinline__ float rawload(const void* p, size_t i, int bfm) {
  return bfm ? __bfloat162float(((const bf*)p)[i]) : ((const float*)p)[i];
}

__global__ void conv_off(const void* __restrict__ src, float* __restrict__ dst,
                         int n, long off, const int* __restrict__ flag) {
  int i = blockIdx.x * 256 + threadIdx.x;
  if (i >= n) return;
  dst[i] = rawload(src, (size_t)off + i, *flag);
}

// transpose + split weight: raw W[K][N] (row stride ldsrc) -> Wh/Wl [N][Kpad]
__global__ void wsplit_t(const void* __restrict__ src, const int* __restrict__ flag,
                         long srcOff, int ldsrc, int K, int N, int Kpad,
                         bf* __restrict__ Wh, bf* __restrict__ Wl) {
  long idx = (long)blockIdx.x * 256 + threadIdx.x;
  if (idx >= (long)N * Kpad) return;
  int n = (int)(idx / Kpad), k = (int)(idx % Kpad);
  float v = (k < K) ? rawload(src, (size_t)srcOff + (size_t)k * ldsrc + n, *flag) : 0.f;
  bf h, l;
  splitf(v, &h, &l);
  Wh[idx] = h; Wl[idx] = l;
}

// ---------- x split: sentinel-fused input -> xh/xl [NG][768] ----------
__global__ void xsplit(const void* __restrict__ inp, const void* __restrict__ sent,
                       const int* __restrict__ fi, const int* __restrict__ fs,
                       bf* __restrict__ xh, bf* __restrict__ xl, int g0, int NG) {
  long idx = (long)blockIdx.x * 256 + threadIdx.x;
  long tot = (long)NG * (kD / 4);
  if (idx >= tot) return;
  int n = (int)(idx / (kD / 4));
  int k = (int)(idx % (kD / 4)) * 4;
  int b = n / kSP, r = n - b * kSP;
  const void* src;
  size_t base;
  int bfm;
  if (r == 0) { src = sent; base = (size_t)k; bfm = *fs; }
  else {
    src = inp;
    base = ((size_t)((g0 + b) * kS + (r - 1))) * kD + k;
    bfm = *fi;
  }
  float v[4];
  if (bfm) {
    ushort4v s = *(const ushort4v*)((const unsigned short*)src + base);
#pragma unroll
    for (int j = 0; j < 4; ++j) {
      bf h; unsigned short u = s[j];
      __builtin_memcpy(&h, &u, 2);
      v[j] = __bfloat162float(h);
    }
  } else {
    floatx4 f4 = *(const floatx4*)((const float*)src + base);
#pragma unroll
    for (int j = 0; j < 4; ++j) v[j] = f4[j];
  }
  ushort4v h4, l4;
#pragma unroll
  for (int j = 0; j < 4; ++j) {
    bf h, l;
    splitf(v[j], &h, &l);
    h4[j] = bfbits(h); l4[j] = bfbits(l);
  }
  size_t o = (size_t)n * kD + k;
  *(ushort4v*)((unsigned short*)xh + o) = h4;
  *(ushort4v*)((unsigned short*)xl + o) = l4;
}

// =================== split-bf16 MFMA GEMM, dbuf global_load_lds staging ===================
constexpr int BM = 128, BN = 128, BK = 32;

template <int EPI, int OUTF32>
__global__ __launch_bounds__(256) void gemm_sp(
    const bf* __restrict__ Ah, const bf* __restrict__ Al, int lda,
    const bf* __restrict__ Bh, const bf* __restrict__ Bl, int ldb,
    bf* __restrict__ Ch, bf* __restrict__ Cl, float* __restrict__ Cf, int ldc,
    int M, int N, int K, const float* __restrict__ bias) {
  __shared__ bf sAh[2][BM][BK];
  __shared__ bf sAl[2][BM][BK];
  __shared__ bf sBh[2][BN][BK];
  __shared__ bf sBl[2][BN][BK];
  const int tid = threadIdx.x;
  const int lane = tid & 63, wave = tid >> 6;
  const int quad = lane >> 4, l15 = lane & 15;
  const int wm = (wave >> 1) * 64, wn = (wave & 1) * 64;
  // XCD swizzle: same-A-panel blocks (same x, all y) -> contiguous swz -> same XCD
  const int gy = gridDim.y;
  const int sw = swz8(blockIdx.x + blockIdx.y * gridDim.x, gridDim.x * gy);
  const int m0 = (sw / gy) * BM, n0 = (sw % gy) * BN;
  const int lrow = lane >> 2, lkof = (lane & 3) * 8;

  const bf *pAh[2], *pAl[2], *pBh[2], *pBl[2];
  int rb[2];
#pragma unroll
  for (int jj = 0; jj < 2; ++jj) {
    rb[jj] = wave * 32 + jj * 16;
    int gm = m0 + rb[jj] + lrow; if (gm > M - 1) gm = M - 1;
    int gn = n0 + rb[jj] + lrow; if (gn > N - 1) gn = N - 1;
    pAh[jj] = Ah + (size_t)gm * lda + lkof;
    pAl[jj] = Al + (size_t)gm * lda + lkof;
    pBh[jj] = Bh + (size_t)gn * ldb + lkof;
    pBl[jj] = Bl + (size_t)gn * ldb + lkof;
  }

  auto stage = [&](int bi, int k0) {
#pragma unroll
    for (int jj = 0; jj < 2; ++jj) {
      gload16(pAh[jj] + k0, &sAh[bi][rb[jj]][0]);
      gload16(pAl[jj] + k0, &sAl[bi][rb[jj]][0]);
      gload16(pBh[jj] + k0, &sBh[bi][rb[jj]][0]);
      gload16(pBl[jj] + k0, &sBl[bi][rb[jj]][0]);
    }
  };

  floatx4 acc[4][4] = {};
  stage(0, 0);
  int cur = 0;
  for (int k0 = 0; k0 < K; k0 += BK) {
    __syncthreads();
    if (k0 + BK < K) stage(cur ^ 1, k0 + BK);
    short8 a_h[4], a_l[4], b_h[4], b_l[4];
#pragma unroll
    for (int t = 0; t < 4; ++t) {
      a_h[t] = *(const short8*)&sAh[cur][wm + t * 16 + l15][quad * 8];
      a_l[t] = *(const short8*)&sAl[cur][wm + t * 16 + l15][quad * 8];
      b_h[t] = *(const short8*)&sBh[cur][wn + t * 16 + l15][quad * 8];
      b_l[t] = *(const short8*)&sBl[cur][wn + t * 16 + l15][quad * 8];
    }
#pragma unroll
    for (int mt = 0; mt < 4; ++mt)
#pragma unroll
      for (int nt = 0; nt < 4; ++nt) {
        acc[mt][nt] = __builtin_amdgcn_mfma_f32_16x16x32_bf16(a_h[mt], b_h[nt], acc[mt][nt], 0, 0, 0);
        acc[mt][nt] = __builtin_amdgcn_mfma_f32_16x16x32_bf16(a_h[mt], b_l[nt], acc[mt][nt], 0, 0, 0);
        acc[mt][nt] = __builtin_amdgcn_mfma_f32_16x16x32_bf16(a_l[mt], b_h[nt], acc[mt][nt], 0, 0, 0);
      }
    cur ^= 1;
  }
#pragma unroll
  for (int mt = 0; mt < 4; ++mt)
#pragma unroll
    for (int reg = 0; reg < 4; ++reg) {
      int m = m0 + wm + mt * 16 + quad * 4 + reg;
      if (m >= M) continue;
#pragma unroll
      for (int nt = 0; nt < 4; ++nt) {
        int n = n0 + wn + nt * 16 + l15;
        if (OUTF32) {
          if (n < N) {
            float v = acc[mt][nt][reg];
            if (EPI >= 1) v += bias[n];
            if (EPI == 1) v = v > 0.f ? v : expm1f(v);
            Cf[(size_t)m * ldc + n] = v;
          }
        } else {
          size_t o = (size_t)m * ldc + n;
          if (n < N) {
            float v = acc[mt][nt][reg];
            if (EPI >= 1) v += bias[n];
            if (EPI == 1) v = v > 0.f ? v : expm1f(v);
            bf h, l;
            splitf(v, &h, &l);
            Ch[o] = h; Cl[o] = l;
          } else if (n < ldc) {
            Ch[o] = __float2bfloat16(0.f);
            Cl[o] = __float2bfloat16(0.f);
          }
        }
      }
    }
}

// ====== batched NT bilinear; F operand has row stride ldf ======
__global__ __launch_bounds__(256) void bilnt_sp(
    const bf* __restrict__ Th, const bf* __restrict__ Tl,   // [GB*257][KA]
    const bf* __restrict__ Fh, const bf* __restrict__ Fl, int ldf,
    float* __restrict__ out, const float* __restrict__ bilb, int bidx,
    int g0, int globOut) {
  __shared__ bf sAh[2][BM][BK];
  __shared__ bf sAl[2][BM][BK];
  __shared__ bf sBh[2][BN][BK];
  __shared__ bf sBl[2][BN][BK];
  const int tid = threadIdx.x;
  const int lane = tid & 63, wave = tid >> 6;
  const int quad = lane >> 4, l15 = lane & 15;
  const int wm = (wave >> 1) * 64, wn = (wave & 1) * 64;
  // swizzle: same-z blocks contiguous -> same XCD
  const int gx = gridDim.x, gxy = gridDim.x * gridDim.y;
  const int sw = swz8(blockIdx.x + gx * blockIdx.y + gxy * blockIdx.z, gxy * gridDim.z);
  const int z = sw / gxy;
  const int rem = sw % gxy;
  const int m0 = (rem % gx) * BM, n0 = (rem / gx) * BN;
  const int lrow = lane >> 2, lkof = (lane & 3) * 8;
  const bf* Ah = Th + (size_t)z * kSP * KA;
  const bf* Al = Tl + (size_t)z * kSP * KA;
  const bf* Bh = Fh + (size_t)z * kSP * ldf;
  const bf* Bl = Fl + (size_t)z * kSP * ldf;

  const bf *pAh[2], *pAl[2], *pBh[2], *pBl[2];
  int rb[2];
#pragma unroll
  for (int jj = 0; jj < 2; ++jj) {
    rb[jj] = wave * 32 + jj * 16;
    int gm = m0 + rb[jj] + lrow; if (gm > kSP - 1) gm = kSP - 1;
    int gn = n0 + rb[jj] + lrow; if (gn > kSP - 1) gn = kSP - 1;
    pAh[jj] = Ah + (size_t)gm * KA + lkof;
    pAl[jj] = Al + (size_t)gm * KA + lkof;
    pBh[jj] = Bh + (size_t)gn * ldf + lkof;
    pBl[jj] = Bl + (size_t)gn * ldf + lkof;
  }

  auto stage = [&](int bi, int k0) {
#pragma unroll
    for (int jj = 0; jj < 2; ++jj) {
      gload16(pAh[jj] + k0, &sAh[bi][rb[jj]][0]);
      gload16(pAl[jj] + k0, &sAl[bi][rb[jj]][0]);
      gload16(pBh[jj] + k0, &sBh[bi][rb[jj]][0]);
      gload16(pBl[jj] + k0, &sBl[bi][rb[jj]][0]);
    }
  };

  floatx4 acc[4][4] = {};
  stage(0, 0);
  int cur = 0;
  for (int k0 = 0; k0 < KA; k0 += BK) {
    __syncthreads();
    if (k0 + BK < KA) stage(cur ^ 1, k0 + BK);
    short8 a_h[4], a_l[4], b_h[4], b_l[4];
#pragma unroll
    for (int t = 0; t < 4; ++t) {
      a_h[t] = *(const short8*)&sAh[cur][wm + t * 16 + l15][quad * 8];
      a_l[t] = *(const short8*)&sAl[cur][wm + t * 16 + l15][quad * 8];
      b_h[t] = *(const short8*)&sBh[cur][wn + t * 16 + l15][quad * 8];
      b_l[t] = *(const short8*)&sBl[cur][wn + t * 16 + l15][quad * 8];
    }
#pragma unroll
    for (int mt = 0; mt < 4; ++mt)
#pragma unroll
      for (int nt = 0; nt < 4; ++nt) {
        acc[mt][nt] = __builtin_amdgcn_mfma_f32_16x16x32_bf16(a_h[mt], b_h[nt], acc[mt][nt], 0, 0, 0);
        acc[mt][nt] = __builtin_amdgcn_mfma_f32_16x16x32_bf16(a_h[mt], b_l[nt], acc[mt][nt], 0, 0, 0);
        acc[mt][nt] = __builtin_amdgcn_mfma_f32_16x16x32_bf16(a_l[mt], b_h[nt], acc[mt][nt], 0, 0, 0);
      }
    cur ^= 1;
  }
  const float sb = bilb[bidx];
  const int bb = globOut ? (g0 + z) : z;
#pragma unroll
  for (int mt = 0; mt < 4; ++mt)
#pragma unroll
    for (int reg = 0; reg < 4; ++reg) {
      int i = m0 + wm + mt * 16 + quad * 4 + reg;
      if (i >= kSP) continue;
      float rowterm = bfval(Ah[(size_t)i * KA + 500]) + bfval(Al[(size_t)i * KA + 500]) + sb;
#pragma unroll
      for (int nt = 0; nt < 4; ++nt) {
        int j = n0 + wn + nt * 16 + l15;
        if (j >= kSP) continue;
        out[((size_t)bb * kSP + i) * kSP + j] = acc[mt][nt][reg] + rowterm;
      }
    }
}

// ------------- per-row softmax + top-8 (+dinv); one wave per row -------------
__global__ void softmax_topk(const float* __restrict__ logits,
                             int* __restrict__ idx8,
                             float* __restrict__ val8,
                             float* __restrict__ dinv) {
  const int row = blockIdx.x;
  const int lane = threadIdx.x;
  const int rowbase = row - (row % kSP);
  const float* L = logits + (size_t)row * kSP;
  float v[5];
  int c[5];
#pragma unroll
  for (int q = 0; q < 5; ++q) {
    int j = lane + q * 64;
    c[q] = j;
    v[q] = (j < kSP) ? L[j] : -INFINITY;
  }
  float m = v[0];
#pragma unroll
  for (int q = 1; q < 5; ++q) m = fmaxf(m, v[q]);
  for (int off = 32; off > 0; off >>= 1) m = fmaxf(m, __shfl_xor(m, off));
  float s = 0.f;
#pragma unroll
  for (int q = 0; q < 5; ++q) s += expf(v[q] - m);
  for (int off = 32; off > 0; off >>= 1) s += __shfl_xor(s, off);
  const float invs = 1.f / s;
  float degsum = 0.f;
  for (int t = 0; t < 8; ++t) {
    float bvv = -INFINITY;
    int bii = kSP;
#pragma unroll
    for (int q = 0; q < 5; ++q)
      if (v[q] > bvv) { bvv = v[q]; bii = c[q]; }
    for (int off = 32; off > 0; off >>= 1) {
      float ov = __shfl_xor(bvv, off);
      int oi = __shfl_xor(bii, off);
      if (ov > bvv || (ov == bvv && oi < bii)) { bvv = ov; bii = oi; }
    }
    float p = expf(bvv - m) * invs;
    degsum += p;
    if (lane == 0) { idx8[row * 8 + t] = rowbase + bii; val8[row * 8 + t] = p; }
#pragma unroll
    for (int q = 0; q < 5; ++q)
      if (c[q] == bii) v[q] = -INFINITY;
  }
  if (lane == 0) dinv[row] = 1.f / sqrtf(1.f + degsum);
}

// ------------- GCN aggregation on interleaved rows [2NG][ldy] -------------
// row r = 2*m + p (m = node, p = head/dept half). Edges indexed by m; gathered
// rows are 2*s + p. Split out (+pad zero) or fp32 out (final: + half offset).
template <int ELU, int OUTF32>
__global__ void gcn_agg(const float* __restrict__ Y, int ldy, int F,
                        const int* __restrict__ idx8, const float* __restrict__ val8,
                        const float* __restrict__ dinv, const float* __restrict__ bias,
                        bf* __restrict__ Zh, bf* __restrict__ Zl,
                        float* __restrict__ Zf, int ldzf, long halfStr) {
  const int r = swz8(blockIdx.x, gridDim.x);
  const int m = r >> 1, p = r & 1;
  __shared__ float w[9];
  __shared__ int srcs[8];
  const int t = threadIdx.x;
  if (t < 8) {
    int s = idx8[m * 8 + t];
    srcs[t] = 2 * s + p;
    w[t] = dinv[m] * val8[m * 8 + t] * dinv[s];
  } else if (t == 8) {
    float di = dinv[m];
    w[8] = di * di;
  }
  __syncthreads();
  const int lim = OUTF32 ? F : ldy;
  for (int f = t * 2; f < lim; f += (int)blockDim.x * 2) {
    size_t on = (size_t)r * ldy + f;
    if (!OUTF32 && f >= F) {
      ushort2v zz = {0, 0};
      *(ushort2v*)((unsigned short*)Zh + on) = zz;
      *(ushort2v*)((unsigned short*)Zl + on) = zz;
      continue;
    }
    floatx2 y0 = *(const floatx2*)(Y + on);
    float a0 = w[8] * y0[0], a1 = w[8] * y0[1];
#pragma unroll
    for (int e = 0; e < 8; ++e) {
      floatx2 ys = *(const floatx2*)(Y + (size_t)srcs[e] * ldy + f);
      a0 += w[e] * ys[0];
      a1 += w[e] * ys[1];
    }
    a0 += bias[f];
    a1 += bias[f + 1];
    if (ELU) {
      a0 = a0 > 0.f ? a0 : expm1f(a0);
      a1 = a1 > 0.f ? a1 : expm1f(a1);
    }
    if (OUTF32) {
      float* zp = Zf + (size_t)p * halfStr + (size_t)m * ldzf + f;
      floatx2 o = {a0, a1};
      *(floatx2*)zp = o;
    } else {
      bf h0, l0, h1, l1;
      splitf(a0, &h0, &l0);
      splitf(a1, &h1, &l1);
      ushort2v hv = {bfbits(h0), bfbits(h1)};
      ushort2v lv = {bfbits(l0), bfbits(l1)};
      *(ushort2v*)((unsigned short*)Zh + on) = hv;
      *(ushort2v*)((unsigned short*)Zl + on) = lv;
    }
  }
}

}  // namespace

extern "C" void kernel_launch(void* const* d_in, const int* in_sizes, int n_in,
                              void* d_out, int out_size, void* d_ws, size_t ws_size,
                              hipStream_t stream) {
  (void)out_size;

  // ---------- size-keyed role mapping ----------
  const int roleSize[20] = {kB * kS * kD, kD,
                            kD * kARC, kARC, kD * kARC, kARC,
                            kD * kTAG, kTAG, kD * kTAG, kTAG,
                            3 * 501 * 501, 3,
                            kARC * kARC, kARC, kARC * kARC, kARC,
                            kTAG * kTAG, kTAG, kTAG * kTAG, kTAG};
  const int roleOcc[20]  = {0, 0, 0, 0, 1, 1, 0, 0, 1, 1, 0, 0,
                            0, 2, 1, 3, 0, 2, 1, 3};
  int roleIdx[20] = {0, 5, 6, 7, 8, 9, 10, 11, 12, 13, 14, 15,
                     16, 17, 18, 19, 20, 21, 22, 23};
  for (int r = 0; r < 20; ++r) {
    int occ = 0, found = -1;
    for (int i = 0; i < n_in; ++i) {
      if (in_sizes[i] == roleSize[r]) {
        if (occ == roleOcc[r]) { found = i; break; }
        ++occ;
      }
    }
    if (found >= 0) roleIdx[r] = found;
    else if (roleIdx[r] >= n_in) roleIdx[r] = 0;
  }
  const void* src_of[20];
  for (int r = 0; r < 20; ++r) src_of[r] = d_in[roleIdx[r]];

  // ---- workspace layout ----
  auto need_bytes = [](int GB) -> size_t {
    size_t NG = (size_t)GB * kSP, s = 0;
    auto al = [&](size_t b) { s += (b + 255) & ~(size_t)255; };
    al(256);                                                  // flags
    al((size_t)NPA * kD * 2); al((size_t)NPA * kD * 2);       // WtAB h,l
    al((size_t)NPT * kD * 2); al((size_t)NPT * kD * 2);       // WtTB h,l
    al(NPA * 4); al(NPT * 4);                                 // bpa, bpt
    for (int i = 0; i < 6; ++i) al((size_t)501 * KA * 2);     // bilWt 3 x h,l
    al(3 * 501 * 4); al(256);                                 // brow, bilbf
    for (int i = 0; i < 4; ++i) al((size_t)kARC * KA * 2);    // c1a/c2a h,l
    for (int i = 0; i < 4; ++i) al((size_t)kTAG * KT * 2);    // c1r/c2r h,l
    al(kARC * 4); al(kARC * 4); al(kTAG * 4); al(kTAG * 4);   // conv biases
    al(NG * kD * 2); al(NG * kD * 2);                         // xh, xl
    al(NG * NPA * 2); al(NG * NPA * 2);                       // FA h,l (interleaved)
    al(NG * NPT * 2); al(NG * NPT * 2);                       // FT h,l
    al(NG * KA * 2); al(NG * KA * 2);                         // T h,l
    al(NG * NPA * 2); al(NG * NPA * 2);                       // Z2 h,l
    al(NG * NPA * 4);                                         // Yf fp32
    al(NG * kSP * 4);                                         // logits
    al(NG * 8 * 4); al(NG * 8 * 4); al(NG * 4);               // edges
    return s;
  };
  int GB = 1;
  for (int cand : {128, 64, 32, 16, 8, 4, 2, 1})
    if (need_bytes(cand) <= ws_size) { GB = cand; break; }
  const int G = kB / GB;
  const int NG = GB * kSP;
  const int mb  = (NG + BM - 1) / BM;
  const int mb2 = (2 * NG + BM - 1) / BM;

  char* ws = (char*)d_ws;
  size_t off = 0;
  auto alloc = [&](size_t bytes) -> void* {
    void* p = ws + off;
    off += (bytes + 255) & ~(size_t)255;
    return p;
  };
  int* flags = (int*)alloc(256);
  bf *WtABh = (bf*)alloc((size_t)NPA * kD * 2), *WtABl = (bf*)alloc((size_t)NPA * kD * 2);
  bf *WtTBh = (bf*)alloc((size_t)NPT * kD * 2), *WtTBl = (bf*)alloc((size_t)NPT * kD * 2);
  float* bpa = (float*)alloc(NPA * 4);
  float* bpt = (float*)alloc(NPT * 4);
  bf* bilWh[3]; bf* bilWl[3];
  for (int k = 0; k < 3; ++k) {
    bilWh[k] = (bf*)alloc((size_t)501 * KA * 2);
    bilWl[k] = (bf*)alloc((size_t)501 * KA * 2);
  }
  float* brow = (float*)alloc(3 * 501 * 4);
  float* bilbf = (float*)alloc(256);
  bf *c1ah = (bf*)alloc((size_t)kARC * KA * 2), *c1al = (bf*)alloc((size_t)kARC * KA * 2);
  bf *c2ah = (bf*)alloc((size_t)kARC * KA * 2), *c2al = (bf*)alloc((size_t)kARC * KA * 2);
  bf *c1rh = (bf*)alloc((size_t)kTAG * KT * 2), *c1rl = (bf*)alloc((size_t)kTAG * KT * 2);
  bf *c2rh = (bf*)alloc((size_t)kTAG * KT * 2), *c2rl = (bf*)alloc((size_t)kTAG * KT * 2);
  float* c1ab = (float*)alloc(kARC * 4);
  float* c2ab = (float*)alloc(kARC * 4);
  float* c1rb = (float*)alloc(kTAG * 4);
  float* c2rb = (float*)alloc(kTAG * 4);
  bf *xh = (bf*)alloc((size_t)NG * kD * 2), *xl = (bf*)alloc((size_t)NG * kD * 2);
  bf *FAh = (bf*)alloc((size_t)NG * NPA * 2), *FAl = (bf*)alloc((size_t)NG * NPA * 2);
  bf *FTh = (bf*)alloc((size_t)NG * NPT * 2), *FTl = (bf*)alloc((size_t)NG * NPT * 2);
  bf *Th = (bf*)alloc((size_t)NG * KA * 2), *Tl = (bf*)alloc((size_t)NG * KA * 2);
  bf *Z2h = (bf*)alloc((size_t)NG * NPA * 2), *Z2l = (bf*)alloc((size_t)NG * NPA * 2);
  float* Yf = (float*)alloc((size_t)NG * NPA * 4);
  float* logits = (float*)alloc((size_t)NG * kSP * 4);
  int*   idx8 = (int*)alloc((size_t)NG * 8 * 4);
  float* val8 = (float*)alloc((size_t)NG * 8 * 4);
  float* dinv = (float*)alloc((size_t)NG * 4);

  // ---- dtype flags ----
  for (int r = 0; r < 20; ++r) {
    int n = roleSize[r];
    int nwords = n / 4; if (nwords < 1) nwords = 1; if (nwords > 64) nwords = 64;
    detect_dtype_n<<<1, 64, 0, stream>>>((const unsigned*)src_of[r], flags + r, nwords);
  }
  auto cvt = [&](int role, float* dst, int n, long o) {
    conv_off<<<(n + 255) / 256, 256, 0, stream>>>(src_of[role], dst, n, o, flags + role);
  };
  auto wsp = [&](int role, long o, int ldsrc, int K, int N, int Kpad, bf* Wh, bf* Wl) {
    long tot = (long)N * Kpad;
    wsplit_t<<<(int)((tot + 255) / 256), 256, 0, stream>>>(src_of[role], flags + role, o,
                                                           ldsrc, K, N, Kpad, Wh, Wl);
  };
  auto zf = [&](void* p, size_t bytes) {
    long n4 = (long)(bytes / 4);
    zerofill<<<(int)((n4 + 255) / 256), 256, 0, stream>>>((unsigned*)p, n4);
  };

  // zero concat weight/bias buffers (fills the 12/28-row pads), then fill halves
  zf(WtABh, (size_t)NPA * kD * 2); zf(WtABl, (size_t)NPA * kD * 2);
  zf(WtTBh, (size_t)NPT * kD * 2); zf(WtTBl, (size_t)NPT * kD * 2);
  zf(bpa, NPA * 4); zf(bpt, NPT * 4);
  wsp(2, 0, kARC, kD, kARC, kD, WtABh, WtABl);
  wsp(4, 0, kARC, kD, kARC, kD, WtABh + (size_t)KA * kD, WtABl + (size_t)KA * kD);
  wsp(6, 0, kTAG, kD, kTAG, kD, WtTBh, WtTBl);
  wsp(8, 0, kTAG, kD, kTAG, kD, WtTBh + (size_t)KT * kD, WtTBl + (size_t)KT * kD);
  cvt(3, bpa, kARC, 0); cvt(5, bpa + KA, kARC, 0);
  cvt(7, bpt, kTAG, 0); cvt(9, bpt + KT, kTAG, 0);
  cvt(11, bilbf, 3, 0);
  cvt(13, c1ab, kARC, 0); cvt(15, c2ab, kARC, 0); cvt(17, c1rb, kTAG, 0); cvt(19, c2rb, kTAG, 0);
  for (int k = 0; k < 3; ++k) {
    wsp(10, (long)k * 501 * 501, 501, 500, 501, KA, bilWh[k], bilWl[k]);
    cvt(10, brow + k * 501, 501, (long)k * 501 * 501 + 500 * 501);
  }
  wsp(12, 0, kARC, kARC, kARC, KA, c1ah, c1al);
  wsp(14, 0, kARC, kARC, kARC, KA, c2ah, c2al);
  wsp(16, 0, kTAG, kTAG, kTAG, KT, c1rh, c1rl);
  wsp(18, 0, kTAG, kTAG, kTAG, KT, c2rh, c2rl);

  float* outp = (float*)d_out;
  const size_t arc_elems = (size_t)kB * kSP * kSP;

  for (int g = 0; g < G; ++g) {
    const int g0 = g * GB;

    {
      long tot = (long)NG * (kD / 4);
      xsplit<<<(int)((tot + 255) / 256), 256, 0, stream>>>(
          src_of[0], src_of[1], flags + 0, flags + 1, xh, xl, g0, NG);
    }
    // merged projections: ARC (head|dept -> [NG][1024]), TAG (-> [NG][256])
    gemm_sp<1, 0><<<dim3(mb, NPA / BN), 256, 0, stream>>>(
        xh, xl, kD, WtABh, WtABl, kD, FAh, FAl, nullptr, NPA, NG, NPA, kD, bpa);
    gemm_sp<1, 0><<<dim3(mb, NPT / BN), 256, 0, stream>>>(
        xh, xl, kD, WtTBh, WtTBl, kD, FTh, FTl, nullptr, NPT, NG, NPT, kD, bpt);

    for (int k = 0; k < 2; ++k) {
      // T = [fHA|1] @ bilW_k : A = head half of FA (row stride NPA)
      gemm_sp<2, 0><<<dim3(mb, 4), 256, 0, stream>>>(
          FAh, FAl, NPA, bilWh[k], bilWl[k], KA, Th, Tl, nullptr, KA, NG, 501, KA,
          brow + k * 501);
      bilnt_sp<<<dim3(3, 3, GB), 256, 0, stream>>>(
          Th, Tl, FAh + KA, FAl + KA, NPA, logits, bilbf, k, g0, 0);
      softmax_topk<<<NG, 64, 0, stream>>>(logits, idx8, val8, dinv);

      // ARC conv: interleaved view [2NG][512], one dispatch per GEMM/agg
      gemm_sp<0, 1><<<dim3(mb2, 4), 256, 0, stream>>>(
          FAh, FAl, KA, c1ah, c1al, KA, nullptr, nullptr, Yf, KA, 2 * NG, kARC, KA, nullptr);
      gcn_agg<1, 0><<<2 * NG, 256, 0, stream>>>(Yf, KA, kARC, idx8, val8, dinv, c1ab,
                                                Z2h, Z2l, nullptr, 0, 0);
      gemm_sp<0, 1><<<dim3(mb2, 4), 256, 0, stream>>>(
          Z2h, Z2l, KA, c2ah, c2al, KA, nullptr, nullptr, Yf, KA, 2 * NG, kARC, KA, nullptr);
      gcn_agg<0, 0><<<2 * NG, 256, 0, stream>>>(Yf, KA, kARC, idx8, val8, dinv, c2ab,
                                                FAh, FAl, nullptr, 0, 0);

      // TAG conv: interleaved view [2NG][128]
      gemm_sp<0, 1><<<dim3(mb2, 1), 256, 0, stream>>>(
          FTh, FTl, KT, c1rh, c1rl, KT, nullptr, nullptr, Yf, KT, 2 * NG, kTAG, KT, nullptr);
      gcn_agg<1, 0><<<2 * NG, 64, 0, stream>>>(Yf, KT, kTAG, idx8, val8, dinv, c1rb,
                                               Z2h, Z2l, nullptr, 0, 0);
      gemm_sp<0, 1><<<dim3(mb2, 1), 256, 0, stream>>>(
          Z2h, Z2l, KT, c2rh, c2rl, KT, nullptr, nullptr, Yf, KT, 2 * NG, kTAG, KT, nullptr);
      if (k == 1) {
        // final tag output -> d_out fp32: head half then dep half (+kN*kTAG)
        float* dst = outp + arc_elems + (size_t)g0 * kSP * kTAG;
        gcn_agg<0, 1><<<2 * NG, 64, 0, stream>>>(Yf, KT, kTAG, idx8, val8, dinv, c2rb,
                                                 nullptr, nullptr, dst, kTAG,
                                                 (long)kN * kTAG);
      } else {
        gcn_agg<0, 0><<<2 * NG, 64, 0, stream>>>(Yf, KT, kTAG, idx8, val8, dinv, c2rb,
                                                 FTh, FTl, nullptr, 0, 0);
      }
    }

    // final bilinear -> d_out fp32
    gemm_sp<2, 0><<<dim3(mb, 4), 256, 0, stream>>>(
        FAh, FAl, NPA, bilWh[2], bilWl[2], KA, Th, Tl, nullptr, KA, NG, 501, KA,
        brow + 2 * 501);
    bilnt_sp<<<dim3(3, 3, GB), 256, 0, stream>>>(
        Th, Tl, FAh + KA, FAl + KA, NPA, outp, bilbf, 2, g0, 1);
  }
}

// Round 5
// 2740.628 us; speedup vs baseline: 1.2423x; 1.0208x over previous
//
#include <hip/hip_runtime.h>
#include <hip/hip_bf16.h>
#include <math.h>
#include <cstddef>

namespace {

constexpr int kB   = 128;
constexpr int kS   = 256;
constexpr int kD   = 768;
constexpr int kSP  = 257;
constexpr int kN   = kB * kSP;
constexpr int kARC = 500;
constexpr int kTAG = 100;
constexpr int KA   = 512;   // padded ARC feature width
constexpr int KT   = 128;   // padded TAG feature width
constexpr int NPA  = 1024;  // concat ARC proj width (512+512)
constexpr int NPT  = 256;   // concat TAG proj width (128+128)

typedef __attribute__((ext_vector_type(8))) short short8;
typedef __attribute__((ext_vector_type(4))) float floatx4;
typedef __attribute__((ext_vector_type(2))) float floatx2;
typedef __attribute__((ext_vector_type(4))) unsigned short ushort4v;
typedef __attribute__((ext_vector_type(2))) unsigned short ushort2v;
typedef __hip_bfloat16 bf;

__device__ __forceinline__ float bfval(bf h) { return __bfloat162float(h); }
__device__ __forceinline__ unsigned short bfbits(bf h) {
  unsigned short u; __builtin_memcpy(&u, &h, 2); return u;
}
__device__ __forceinline__ void splitf(float x, bf* h, bf* l) {
  bf hh = __float2bfloat16(x);
  *h = hh;
  *l = __float2bfloat16(x - __bfloat162float(hh));
}

// bijective XCD chunking (m204): contiguous swz ranges land on one XCD
__device__ __forceinline__ int swz8(int lid, int total) {
  int q = total >> 3, r = total & 7;
  int c = lid & 7, p = lid >> 3;
  return (c < r ? c * (q + 1) : r * (q + 1) + (c - r) * q) + p;
}

// async global -> LDS, 16B per lane; LDS dest is wave-uniform base + lane*16
__device__ __forceinline__ void gload16(const bf* g, bf* l) {
  __builtin_amdgcn_global_load_lds(
      (const __attribute__((address_space(1))) void*)g,
      (__attribute__((address_space(3))) void*)l, 16, 0, 0);
}

__global__ void zerofill(unsigned* __restrict__ p, long n4) {
  long i = (long)blockIdx.x * 256 + threadIdx.x;
  if (i < n4) p[i] = 0u;
}

// ---------- per-tensor dtype detection (1 = bf16 storage, 0 = fp32) ----------
__global__ void detect_dtype_n(const unsigned* __restrict__ raw, int* __restrict__ flag,
                               int nwords) {
  int lane = threadIdx.x;
  int ok = 0, nz = 0;
  if (lane < nwords) {
    unsigned w = raw[lane];
    if (w != 0u) {
      nz = 1;
      int e = (w >> 7) & 0xFF;
      ok = (e >= 90 && e <= 140);
    }
  }
  unsigned long long ball_ok = __ballot(ok);
  unsigned long long ball_nz = __ballot(nz);
  if (lane == 0) {
    int cok = __popcll(ball_ok), cnz = __popcll(ball_nz);
    flag[0] = (cok * 4 >= cnz * 3) ? 1 : 0;
  }
}

__device__ __forceinline__ float rawload(const void* p, size_t i, int bfm) {
  return bfm ? __bfloat162float(((const bf*)p)[i]) : ((const float*)p)[i];
}

__global__ void conv_off(const void* __restrict__ src, float* __restrict__ dst,
                         int n, long off, const int* __restrict__ flag) {
  int i = blockIdx.x * 256 + threadIdx.x;
  if (i >= n) return;
  dst[i] = rawload(src, (size_t)off + i, *flag);
}

// transpose + split weight: raw W[K][N] (row stride ldsrc) -> Wh/Wl [N][Kpad]
__global__ void wsplit_t(const void* __restrict__ src, const int* __restrict__ flag,
                         long srcOff, int ldsrc, int K, int N, int Kpad,
                         bf* __restrict__ Wh, bf* __restrict__ Wl) {
  long idx = (long)blockIdx.x * 256 + threadIdx.x;
  if (idx >= (long)N * Kpad) return;
  int n = (int)(idx / Kpad), k = (int)(idx % Kpad);
  float v = (k < K) ? rawload(src, (size_t)srcOff + (size_t)k * ldsrc + n, *flag) : 0.f;
  bf h, l;
  splitf(v, &h, &l);
  Wh[idx] = h; Wl[idx] = l;
}

// ---------- x split: sentinel-fused input -> xh/xl [NG][768] ----------
__global__ void xsplit(const void* __restrict__ inp, const void* __restrict__ sent,
                       const int* __restrict__ fi, const int* __restrict__ fs,
                       bf* __restrict__ xh, bf* __restrict__ xl, int g0, int NG) {
  long idx = (long)blockIdx.x * 256 + threadIdx.x;
  long tot = (long)NG * (kD / 4);
  if (idx >= tot) return;
  int n = (int)(idx / (kD / 4));
  int k = (int)(idx % (kD / 4)) * 4;
  int b = n / kSP, r = n - b * kSP;
  const void* src;
  size_t base;
  int bfm;
  if (r == 0) { src = sent; base = (size_t)k; bfm = *fs; }
  else {
    src = inp;
    base = ((size_t)((g0 + b) * kS + (r - 1))) * kD + k;
    bfm = *fi;
  }
  float v[4];
  if (bfm) {
    ushort4v s = *(const ushort4v*)((const unsigned short*)src + base);
#pragma unroll
    for (int j = 0; j < 4; ++j) {
      bf h; unsigned short u = s[j];
      __builtin_memcpy(&h, &u, 2);
      v[j] = __bfloat162float(h);
    }
  } else {
    floatx4 f4 = *(const floatx4*)((const float*)src + base);
#pragma unroll
    for (int j = 0; j < 4; ++j) v[j] = f4[j];
  }
  ushort4v h4, l4;
#pragma unroll
  for (int j = 0; j < 4; ++j) {
    bf h, l;
    splitf(v[j], &h, &l);
    h4[j] = bfbits(h); l4[j] = bfbits(l);
  }
  size_t o = (size_t)n * kD + k;
  *(ushort4v*)((unsigned short*)xh + o) = h4;
  *(ushort4v*)((unsigned short*)xl + o) = l4;
}

// =================== split-bf16 MFMA GEMM, dbuf global_load_lds staging ===================
constexpr int BM = 128, BN = 128, BK = 32;

template <int EPI, int OUTF32>
__global__ __launch_bounds__(256) void gemm_sp(
    const bf* __restrict__ Ah, const bf* __restrict__ Al, int lda,
    const bf* __restrict__ Bh, const bf* __restrict__ Bl, int ldb,
    bf* __restrict__ Ch, bf* __restrict__ Cl, float* __restrict__ Cf, int ldc,
    int M, int N, int K, const float* __restrict__ bias) {
  __shared__ bf sAh[2][BM][BK];
  __shared__ bf sAl[2][BM][BK];
  __shared__ bf sBh[2][BN][BK];
  __shared__ bf sBl[2][BN][BK];
  const int tid = threadIdx.x;
  const int lane = tid & 63, wave = tid >> 6;
  const int quad = lane >> 4, l15 = lane & 15;
  const int wm = (wave >> 1) * 64, wn = (wave & 1) * 64;
  // XCD swizzle: same-A-panel blocks (same x, all y) -> contiguous swz -> same XCD
  const int gy = gridDim.y;
  const int sw = swz8(blockIdx.x + blockIdx.y * gridDim.x, gridDim.x * gy);
  const int m0 = (sw / gy) * BM, n0 = (sw % gy) * BN;
  const int lrow = lane >> 2, lkof = (lane & 3) * 8;

  const bf *pAh[2], *pAl[2], *pBh[2], *pBl[2];
  int rb[2];
#pragma unroll
  for (int jj = 0; jj < 2; ++jj) {
    rb[jj] = wave * 32 + jj * 16;
    int gm = m0 + rb[jj] + lrow; if (gm > M - 1) gm = M - 1;
    int gn = n0 + rb[jj] + lrow; if (gn > N - 1) gn = N - 1;
    pAh[jj] = Ah + (size_t)gm * lda + lkof;
    pAl[jj] = Al + (size_t)gm * lda + lkof;
    pBh[jj] = Bh + (size_t)gn * ldb + lkof;
    pBl[jj] = Bl + (size_t)gn * ldb + lkof;
  }

  auto stage = [&](int bi, int k0) {
#pragma unroll
    for (int jj = 0; jj < 2; ++jj) {
      gload16(pAh[jj] + k0, &sAh[bi][rb[jj]][0]);
      gload16(pAl[jj] + k0, &sAl[bi][rb[jj]][0]);
      gload16(pBh[jj] + k0, &sBh[bi][rb[jj]][0]);
      gload16(pBl[jj] + k0, &sBl[bi][rb[jj]][0]);
    }
  };

  floatx4 acc[4][4] = {};
  stage(0, 0);
  int cur = 0;
  for (int k0 = 0; k0 < K; k0 += BK) {
    __syncthreads();
    if (k0 + BK < K) stage(cur ^ 1, k0 + BK);
    short8 a_h[4], a_l[4], b_h[4], b_l[4];
#pragma unroll
    for (int t = 0; t < 4; ++t) {
      a_h[t] = *(const short8*)&sAh[cur][wm + t * 16 + l15][quad * 8];
      a_l[t] = *(const short8*)&sAl[cur][wm + t * 16 + l15][quad * 8];
      b_h[t] = *(const short8*)&sBh[cur][wn + t * 16 + l15][quad * 8];
      b_l[t] = *(const short8*)&sBl[cur][wn + t * 16 + l15][quad * 8];
    }
#pragma unroll
    for (int mt = 0; mt < 4; ++mt)
#pragma unroll
      for (int nt = 0; nt < 4; ++nt) {
        acc[mt][nt] = __builtin_amdgcn_mfma_f32_16x16x32_bf16(a_h[mt], b_h[nt], acc[mt][nt], 0, 0, 0);
        acc[mt][nt] = __builtin_amdgcn_mfma_f32_16x16x32_bf16(a_h[mt], b_l[nt], acc[mt][nt], 0, 0, 0);
        acc[mt][nt] = __builtin_amdgcn_mfma_f32_16x16x32_bf16(a_l[mt], b_h[nt], acc[mt][nt], 0, 0, 0);
      }
    cur ^= 1;
  }
#pragma unroll
  for (int mt = 0; mt < 4; ++mt)
#pragma unroll
    for (int reg = 0; reg < 4; ++reg) {
      int m = m0 + wm + mt * 16 + quad * 4 + reg;
      if (m >= M) continue;
#pragma unroll
      for (int nt = 0; nt < 4; ++nt) {
        int n = n0 + wn + nt * 16 + l15;
        if (OUTF32) {
          if (n < N) {
            float v = acc[mt][nt][reg];
            if (EPI >= 1) v += bias[n];
            if (EPI == 1) v = v > 0.f ? v : expm1f(v);
            Cf[(size_t)m * ldc + n] = v;
          }
        } else {
          size_t o = (size_t)m * ldc + n;
          if (n < N) {
            float v = acc[mt][nt][reg];
            if (EPI >= 1) v += bias[n];
            if (EPI == 1) v = v > 0.f ? v : expm1f(v);
            bf h, l;
            splitf(v, &h, &l);
            Ch[o] = h; Cl[o] = l;
          } else if (n < ldc) {
            Ch[o] = __float2bfloat16(0.f);
            Cl[o] = __float2bfloat16(0.f);
          }
        }
      }
    }
}

// ====== batched NT bilinear; F operand has row stride ldf ======
__global__ __launch_bounds__(256) void bilnt_sp(
    const bf* __restrict__ Th, const bf* __restrict__ Tl,   // [GB*257][KA]
    const bf* __restrict__ Fh, const bf* __restrict__ Fl, int ldf,
    float* __restrict__ out, const float* __restrict__ bilb, int bidx,
    int g0, int globOut) {
  __shared__ bf sAh[2][BM][BK];
  __shared__ bf sAl[2][BM][BK];
  __shared__ bf sBh[2][BN][BK];
  __shared__ bf sBl[2][BN][BK];
  const int tid = threadIdx.x;
  const int lane = tid & 63, wave = tid >> 6;
  const int quad = lane >> 4, l15 = lane & 15;
  const int wm = (wave >> 1) * 64, wn = (wave & 1) * 64;
  const int gx = gridDim.x, gxy = gridDim.x * gridDim.y;
  const int sw = swz8(blockIdx.x + gx * blockIdx.y + gxy * blockIdx.z, gxy * gridDim.z);
  const int z = sw / gxy;
  const int rem = sw % gxy;
  const int m0 = (rem % gx) * BM, n0 = (rem / gx) * BN;
  const int lrow = lane >> 2, lkof = (lane & 3) * 8;
  const bf* Ah = Th + (size_t)z * kSP * KA;
  const bf* Al = Tl + (size_t)z * kSP * KA;
  const bf* Bh = Fh + (size_t)z * kSP * ldf;
  const bf* Bl = Fl + (size_t)z * kSP * ldf;

  const bf *pAh[2], *pAl[2], *pBh[2], *pBl[2];
  int rb[2];
#pragma unroll
  for (int jj = 0; jj < 2; ++jj) {
    rb[jj] = wave * 32 + jj * 16;
    int gm = m0 + rb[jj] + lrow; if (gm > kSP - 1) gm = kSP - 1;
    int gn = n0 + rb[jj] + lrow; if (gn > kSP - 1) gn = kSP - 1;
    pAh[jj] = Ah + (size_t)gm * KA + lkof;
    pAl[jj] = Al + (size_t)gm * KA + lkof;
    pBh[jj] = Bh + (size_t)gn * ldf + lkof;
    pBl[jj] = Bl + (size_t)gn * ldf + lkof;
  }

  auto stage = [&](int bi, int k0) {
#pragma unroll
    for (int jj = 0; jj < 2; ++jj) {
      gload16(pAh[jj] + k0, &sAh[bi][rb[jj]][0]);
      gload16(pAl[jj] + k0, &sAl[bi][rb[jj]][0]);
      gload16(pBh[jj] + k0, &sBh[bi][rb[jj]][0]);
      gload16(pBl[jj] + k0, &sBl[bi][rb[jj]][0]);
    }
  };

  floatx4 acc[4][4] = {};
  stage(0, 0);
  int cur = 0;
  for (int k0 = 0; k0 < KA; k0 += BK) {
    __syncthreads();
    if (k0 + BK < KA) stage(cur ^ 1, k0 + BK);
    short8 a_h[4], a_l[4], b_h[4], b_l[4];
#pragma unroll
    for (int t = 0; t < 4; ++t) {
      a_h[t] = *(const short8*)&sAh[cur][wm + t * 16 + l15][quad * 8];
      a_l[t] = *(const short8*)&sAl[cur][wm + t * 16 + l15][quad * 8];
      b_h[t] = *(const short8*)&sBh[cur][wn + t * 16 + l15][quad * 8];
      b_l[t] = *(const short8*)&sBl[cur][wn + t * 16 + l15][quad * 8];
    }
#pragma unroll
    for (int mt = 0; mt < 4; ++mt)
#pragma unroll
      for (int nt = 0; nt < 4; ++nt) {
        acc[mt][nt] = __builtin_amdgcn_mfma_f32_16x16x32_bf16(a_h[mt], b_h[nt], acc[mt][nt], 0, 0, 0);
        acc[mt][nt] = __builtin_amdgcn_mfma_f32_16x16x32_bf16(a_h[mt], b_l[nt], acc[mt][nt], 0, 0, 0);
        acc[mt][nt] = __builtin_amdgcn_mfma_f32_16x16x32_bf16(a_l[mt], b_h[nt], acc[mt][nt], 0, 0, 0);
      }
    cur ^= 1;
  }
  const float sb = bilb[bidx];
  const int bb = globOut ? (g0 + z) : z;
#pragma unroll
  for (int mt = 0; mt < 4; ++mt)
#pragma unroll
    for (int reg = 0; reg < 4; ++reg) {
      int i = m0 + wm + mt * 16 + quad * 4 + reg;
      if (i >= kSP) continue;
      float rowterm = bfval(Ah[(size_t)i * KA + 500]) + bfval(Al[(size_t)i * KA + 500]) + sb;
#pragma unroll
      for (int nt = 0; nt < 4; ++nt) {
        int j = n0 + wn + nt * 16 + l15;
        if (j >= kSP) continue;
        out[((size_t)bb * kSP + i) * kSP + j] = acc[mt][nt][reg] + rowterm;
      }
    }
}

// ------------- per-row softmax + top-8 (+dinv); one wave per row -------------
// idx8 stores the LOCAL column index (0..256) as ushort; agg adds the batch base.
__global__ void softmax_topk(const float* __restrict__ logits,
                             unsigned short* __restrict__ idx8,
                             float* __restrict__ val8,
                             float* __restrict__ dinv) {
  const int row = blockIdx.x;
  const int lane = threadIdx.x;
  const float* L = logits + (size_t)row * kSP;
  float v[5];
  int c[5];
#pragma unroll
  for (int q = 0; q < 5; ++q) {
    int j = lane + q * 64;
    c[q] = j;
    v[q] = (j < kSP) ? L[j] : -INFINITY;
  }
  float m = v[0];
#pragma unroll
  for (int q = 1; q < 5; ++q) m = fmaxf(m, v[q]);
  for (int off = 32; off > 0; off >>= 1) m = fmaxf(m, __shfl_xor(m, off));
  float s = 0.f;
#pragma unroll
  for (int q = 0; q < 5; ++q) s += expf(v[q] - m);
  for (int off = 32; off > 0; off >>= 1) s += __shfl_xor(s, off);
  const float invs = 1.f / s;
  float degsum = 0.f;
  for (int t = 0; t < 8; ++t) {
    float bvv = -INFINITY;
    int bii = 0;
#pragma unroll
    for (int q = 0; q < 5; ++q)
      if (v[q] > bvv) { bvv = v[q]; bii = c[q]; }
    for (int off = 32; off > 0; off >>= 1) {
      float ov = __shfl_xor(bvv, off);
      int oi = __shfl_xor(bii, off);
      if (ov > bvv || (ov == bvv && oi < bii)) { bvv = ov; bii = oi; }
    }
    float p = expf(bvv - m) * invs;
    degsum += p;
    if (lane == 0) { idx8[row * 8 + t] = (unsigned short)bii; val8[row * 8 + t] = p; }
#pragma unroll
    for (int q = 0; q < 5; ++q)
      if (c[q] == bii) v[q] = -INFINITY;
  }
  if (lane == 0) dinv[row] = 1.f / sqrtf(1.f + degsum);
}

// ------------- GCN aggregation on interleaved rows [2NG][ldy] -------------
template <int ELU, int OUTF32>
__global__ void gcn_agg(const float* __restrict__ Y, int ldy, int F,
                        const unsigned short* __restrict__ idx8,
                        const float* __restrict__ val8,
                        const float* __restrict__ dinv, const float* __restrict__ bias,
                        bf* __restrict__ Zh, bf* __restrict__ Zl,
                        float* __restrict__ Zf, int ldzf, long halfStr) {
  const int r = swz8(blockIdx.x, gridDim.x);
  const int m = r >> 1, p = r & 1;
  __shared__ float w[9];
  __shared__ int srcs[8];
  const int t = threadIdx.x;
  if (t < 8) {
    int b0 = m - (m % kSP);
    int s = b0 + (int)idx8[m * 8 + t];
    srcs[t] = 2 * s + p;
    w[t] = dinv[m] * val8[m * 8 + t] * dinv[s];
  } else if (t == 8) {
    float di = dinv[m];
    w[8] = di * di;
  }
  __syncthreads();
  const int lim = OUTF32 ? F : ldy;
  for (int f = t * 2; f < lim; f += (int)blockDim.x * 2) {
    size_t on = (size_t)r * ldy + f;
    if (!OUTF32 && f >= F) {
      ushort2v zz = {0, 0};
      *(ushort2v*)((unsigned short*)Zh + on) = zz;
      *(ushort2v*)((unsigned short*)Zl + on) = zz;
      continue;
    }
    floatx2 y0 = *(const floatx2*)(Y + on);
    float a0 = w[8] * y0[0], a1 = w[8] * y0[1];
#pragma unroll
    for (int e = 0; e < 8; ++e) {
      floatx2 ys = *(const floatx2*)(Y + (size_t)srcs[e] * ldy + f);
      a0 += w[e] * ys[0];
      a1 += w[e] * ys[1];
    }
    a0 += bias[f];
    a1 += bias[f + 1];
    if (ELU) {
      a0 = a0 > 0.f ? a0 : expm1f(a0);
      a1 = a1 > 0.f ? a1 : expm1f(a1);
    }
    if (OUTF32) {
      float* zp = Zf + (size_t)p * halfStr + (size_t)m * ldzf + f;
      floatx2 o = {a0, a1};
      *(floatx2*)zp = o;
    } else {
      bf h0, l0, h1, l1;
      splitf(a0, &h0, &l0);
      splitf(a1, &h1, &l1);
      ushort2v hv = {bfbits(h0), bfbits(h1)};
      ushort2v lv = {bfbits(l0), bfbits(l1)};
      *(ushort2v*)((unsigned short*)Zh + on) = hv;
      *(ushort2v*)((unsigned short*)Zl + on) = lv;
    }
  }
}

}  // namespace

extern "C" void kernel_launch(void* const* d_in, const int* in_sizes, int n_in,
                              void* d_out, int out_size, void* d_ws, size_t ws_size,
                              hipStream_t stream) {
  (void)out_size;

  // ---------- size-keyed role mapping ----------
  const int roleSize[20] = {kB * kS * kD, kD,
                            kD * kARC, kARC, kD * kARC, kARC,
                            kD * kTAG, kTAG, kD * kTAG, kTAG,
                            3 * 501 * 501, 3,
                            kARC * kARC, kARC, kARC * kARC, kARC,
                            kTAG * kTAG, kTAG, kTAG * kTAG, kTAG};
  const int roleOcc[20]  = {0, 0, 0, 0, 1, 1, 0, 0, 1, 1, 0, 0,
                            0, 2, 1, 3, 0, 2, 1, 3};
  int roleIdx[20] = {0, 5, 6, 7, 8, 9, 10, 11, 12, 13, 14, 15,
                     16, 17, 18, 19, 20, 21, 22, 23};
  for (int r = 0; r < 20; ++r) {
    int occ = 0, found = -1;
    for (int i = 0; i < n_in; ++i) {
      if (in_sizes[i] == roleSize[r]) {
        if (occ == roleOcc[r]) { found = i; break; }
        ++occ;
      }
    }
    if (found >= 0) roleIdx[r] = found;
    else if (roleIdx[r] >= n_in) roleIdx[r] = 0;
  }
  const void* src_of[20];
  for (int r = 0; r < 20; ++r) src_of[r] = d_in[roleIdx[r]];

  // ---- workspace layout with phase-disjoint aliasing ----
  // R1 = { xh+xl (proj) | Th+Tl+logits (bilinear) | Yf (conv) }
  // R2 = { Z2h+Z2l }
  auto r1_bytes = [](size_t NG) -> size_t {
    size_t a = (size_t)2 * NG * KA * 4;                       // Yf fp32 [2NG][KA]
    size_t b = NG * kD * 2 * 2;                               // xh+xl
    size_t c = NG * KA * 2 * 2 + NG * kSP * 4;                // T h,l + logits
    size_t m = a; if (b > m) m = b; if (c > m) m = c;
    return m;
  };
  auto need_bytes = [&](int GB) -> size_t {
    size_t NG = (size_t)GB * kSP, s = 0;
    auto al = [&](size_t b) { s += (b + 255) & ~(size_t)255; };
    al(256);                                                  // flags
    al((size_t)NPA * kD * 2); al((size_t)NPA * kD * 2);       // WtAB h,l
    al((size_t)NPT * kD * 2); al((size_t)NPT * kD * 2);       // WtTB h,l
    al(NPA * 4); al(NPT * 4);                                 // bpa, bpt
    for (int i = 0; i < 6; ++i) al((size_t)501 * KA * 2);     // bilWt 3 x h,l
    al(3 * 501 * 4); al(256);                                 // brow, bilbf
    for (int i = 0; i < 4; ++i) al((size_t)kARC * KA * 2);    // c1a/c2a h,l
    for (int i = 0; i < 4; ++i) al((size_t)kTAG * KT * 2);    // c1r/c2r h,l
    al(kARC * 4); al(kARC * 4); al(kTAG * 4); al(kTAG * 4);   // conv biases
    al(NG * NPA * 2); al(NG * NPA * 2);                       // FA h,l
    al(NG * NPT * 2); al(NG * NPT * 2);                       // FT h,l
    al(r1_bytes(NG));                                         // R1
    al((size_t)2 * NG * KA * 2 * 2);                          // R2 (Z2 h+l)
    al(NG * 8 * 2); al(NG * 8 * 4); al(NG * 4);               // edges (ushort idx)
    return s;
  };
  int GB = 1;
  for (int cand : {128, 64, 32, 16, 8, 4, 2, 1})
    if (need_bytes(cand) <= ws_size) { GB = cand; break; }
  const int G = kB / GB;
  const int NG = GB * kSP;
  const int mb  = (NG + BM - 1) / BM;
  const int mb2 = (2 * NG + BM - 1) / BM;

  char* ws = (char*)d_ws;
  size_t off = 0;
  auto alloc = [&](size_t bytes) -> void* {
    void* p = ws + off;
    off += (bytes + 255) & ~(size_t)255;
    return p;
  };
  int* flags = (int*)alloc(256);
  bf *WtABh = (bf*)alloc((size_t)NPA * kD * 2), *WtABl = (bf*)alloc((size_t)NPA * kD * 2);
  bf *WtTBh = (bf*)alloc((size_t)NPT * kD * 2), *WtTBl = (bf*)alloc((size_t)NPT * kD * 2);
  float* bpa = (float*)alloc(NPA * 4);
  float* bpt = (float*)alloc(NPT * 4);
  bf* bilWh[3]; bf* bilWl[3];
  for (int k = 0; k < 3; ++k) {
    bilWh[k] = (bf*)alloc((size_t)501 * KA * 2);
    bilWl[k] = (bf*)alloc((size_t)501 * KA * 2);
  }
  float* brow = (float*)alloc(3 * 501 * 4);
  float* bilbf = (float*)alloc(256);
  bf *c1ah = (bf*)alloc((size_t)kARC * KA * 2), *c1al = (bf*)alloc((size_t)kARC * KA * 2);
  bf *c2ah = (bf*)alloc((size_t)kARC * KA * 2), *c2al = (bf*)alloc((size_t)kARC * KA * 2);
  bf *c1rh = (bf*)alloc((size_t)kTAG * KT * 2), *c1rl = (bf*)alloc((size_t)kTAG * KT * 2);
  bf *c2rh = (bf*)alloc((size_t)kTAG * KT * 2), *c2rl = (bf*)alloc((size_t)kTAG * KT * 2);
  float* c1ab = (float*)alloc(kARC * 4);
  float* c2ab = (float*)alloc(kARC * 4);
  float* c1rb = (float*)alloc(kTAG * 4);
  float* c2rb = (float*)alloc(kTAG * 4);
  bf *FAh = (bf*)alloc((size_t)NG * NPA * 2), *FAl = (bf*)alloc((size_t)NG * NPA * 2);
  bf *FTh = (bf*)alloc((size_t)NG * NPT * 2), *FTl = (bf*)alloc((size_t)NG * NPT * 2);
  char* R1 = (char*)alloc(r1_bytes((size_t)NG));
  bf* xh = (bf*)R1;
  bf* xl = xh + (size_t)NG * kD;
  bf* Th = (bf*)R1;
  bf* Tl = Th + (size_t)NG * KA;
  float* logits = (float*)(R1 + (size_t)NG * KA * 2 * 2);
  float* Yf = (float*)R1;
  bf* Z2h = (bf*)alloc((size_t)2 * NG * KA * 2 * 2);
  bf* Z2l = Z2h + (size_t)2 * NG * KA;
  unsigned short* idx8 = (unsigned short*)alloc((size_t)NG * 8 * 2);
  float* val8 = (float*)alloc((size_t)NG * 8 * 4);
  float* dinv = (float*)alloc((size_t)NG * 4);

  // ---- dtype flags ----
  for (int r = 0; r < 20; ++r) {
    int n = roleSize[r];
    int nwords = n / 4; if (nwords < 1) nwords = 1; if (nwords > 64) nwords = 64;
    detect_dtype_n<<<1, 64, 0, stream>>>((const unsigned*)src_of[r], flags + r, nwords);
  }
  auto cvt = [&](int role, float* dst, int n, long o) {
    conv_off<<<(n + 255) / 256, 256, 0, stream>>>(src_of[role], dst, n, o, flags + role);
  };
  auto wsp = [&](int role, long o, int ldsrc, int K, int N, int Kpad, bf* Wh, bf* Wl) {
    long tot = (long)N * Kpad;
    wsplit_t<<<(int)((tot + 255) / 256), 256, 0, stream>>>(src_of[role], flags + role, o,
                                                           ldsrc, K, N, Kpad, Wh, Wl);
  };
  auto zf = [&](void* p, size_t bytes) {
    long n4 = (long)(bytes / 4);
    zerofill<<<(int)((n4 + 255) / 256), 256, 0, stream>>>((unsigned*)p, n4);
  };

  zf(WtABh, (size_t)NPA * kD * 2); zf(WtABl, (size_t)NPA * kD * 2);
  zf(WtTBh, (size_t)NPT * kD * 2); zf(WtTBl, (size_t)NPT * kD * 2);
  zf(bpa, NPA * 4); zf(bpt, NPT * 4);
  wsp(2, 0, kARC, kD, kARC, kD, WtABh, WtABl);
  wsp(4, 0, kARC, kD, kARC, kD, WtABh + (size_t)KA * kD, WtABl + (size_t)KA * kD);
  wsp(6, 0, kTAG, kD, kTAG, kD, WtTBh, WtTBl);
  wsp(8, 0, kTAG, kD, kTAG, kD, WtTBh + (size_t)KT * kD, WtTBl + (size_t)KT * kD);
  cvt(3, bpa, kARC, 0); cvt(5, bpa + KA, kARC, 0);
  cvt(7, bpt, kTAG, 0); cvt(9, bpt + KT, kTAG, 0);
  cvt(11, bilbf, 3, 0);
  cvt(13, c1ab, kARC, 0); cvt(15, c2ab, kARC, 0); cvt(17, c1rb, kTAG, 0); cvt(19, c2rb, kTAG, 0);
  for (int k = 0; k < 3; ++k) {
    wsp(10, (long)k * 501 * 501, 501, 500, 501, KA, bilWh[k], bilWl[k]);
    cvt(10, brow + k * 501, 501, (long)k * 501 * 501 + 500 * 501);
  }
  wsp(12, 0, kARC, kARC, kARC, KA, c1ah, c1al);
  wsp(14, 0, kARC, kARC, kARC, KA, c2ah, c2al);
  wsp(16, 0, kTAG, kTAG, kTAG, KT, c1rh, c1rl);
  wsp(18, 0, kTAG, kTAG, kTAG, KT, c2rh, c2rl);

  float* outp = (float*)d_out;
  const size_t arc_elems = (size_t)kB * kSP * kSP;

  for (int g = 0; g < G; ++g) {
    const int g0 = g * GB;

    {
      long tot = (long)NG * (kD / 4);
      xsplit<<<(int)((tot + 255) / 256), 256, 0, stream>>>(
          src_of[0], src_of[1], flags + 0, flags + 1, xh, xl, g0, NG);
    }
    // merged projections: ARC (head|dept -> [NG][1024]), TAG (-> [NG][256])
    gemm_sp<1, 0><<<dim3(mb, NPA / BN), 256, 0, stream>>>(
        xh, xl, kD, WtABh, WtABl, kD, FAh, FAl, nullptr, NPA, NG, NPA, kD, bpa);
    gemm_sp<1, 0><<<dim3(mb, NPT / BN), 256, 0, stream>>>(
        xh, xl, kD, WtTBh, WtTBl, kD, FTh, FTl, nullptr, NPT, NG, NPT, kD, bpt);

    for (int k = 0; k < 2; ++k) {
      // T = [fHA|1] @ bilW_k : A = head half of FA (row stride NPA)
      gemm_sp<2, 0><<<dim3(mb, 4), 256, 0, stream>>>(
          FAh, FAl, NPA, bilWh[k], bilWl[k], KA, Th, Tl, nullptr, KA, NG, 501, KA,
          brow + k * 501);
      bilnt_sp<<<dim3(3, 3, GB), 256, 0, stream>>>(
          Th, Tl, FAh + KA, FAl + KA, NPA, logits, bilbf, k, g0, 0);
      softmax_topk<<<NG, 64, 0, stream>>>(logits, idx8, val8, dinv);

      // ARC conv: interleaved view [2NG][512]
      gemm_sp<0, 1><<<dim3(mb2, 4), 256, 0, stream>>>(
          FAh, FAl, KA, c1ah, c1al, KA, nullptr, nullptr, Yf, KA, 2 * NG, kARC, KA, nullptr);
      gcn_agg<1, 0><<<2 * NG, 256, 0, stream>>>(Yf, KA, kARC, idx8, val8, dinv, c1ab,
                                                Z2h, Z2l, nullptr, 0, 0);
      gemm_sp<0, 1><<<dim3(mb2, 4), 256, 0, stream>>>(
          Z2h, Z2l, KA, c2ah, c2al, KA, nullptr, nullptr, Yf, KA, 2 * NG, kARC, KA, nullptr);
      gcn_agg<0, 0><<<2 * NG, 256, 0, stream>>>(Yf, KA, kARC, idx8, val8, dinv, c2ab,
                                                FAh, FAl, nullptr, 0, 0);

      // TAG conv: interleaved view [2NG][128]
      gemm_sp<0, 1><<<dim3(mb2, 1), 256, 0, stream>>>(
          FTh, FTl, KT, c1rh, c1rl, KT, nullptr, nullptr, Yf, KT, 2 * NG, kTAG, KT, nullptr);
      gcn_agg<1, 0><<<2 * NG, 64, 0, stream>>>(Yf, KT, kTAG, idx8, val8, dinv, c1rb,
                                               Z2h, Z2l, nullptr, 0, 0);
      gemm_sp<0, 1><<<dim3(mb2, 1), 256, 0, stream>>>(
          Z2h, Z2l, KT, c2rh, c2rl, KT, nullptr, nullptr, Yf, KT, 2 * NG, kTAG, KT, nullptr);
      if (k == 1) {
        float* dst = outp + arc_elems + (size_t)g0 * kSP * kTAG;
        gcn_agg<0, 1><<<2 * NG, 64, 0, stream>>>(Yf, KT, kTAG, idx8, val8, dinv, c2rb,
                                                 nullptr, nullptr, dst, kTAG,
                                                 (long)kN * kTAG);
      } else {
        gcn_agg<0, 0><<<2 * NG, 64, 0, stream>>>(Yf, KT, kTAG, idx8, val8, dinv, c2rb,
                                                 FTh, FTl, nullptr, 0, 0);
      }
    }

    // final bilinear -> d_out fp32
    gemm_sp<2, 0><<<dim3(mb, 4), 256, 0, stream>>>(
        FAh, FAl, NPA, bilWh[2], bilWl[2], KA, Th, Tl, nullptr, KA, NG, 501, KA,
        brow + 2 * 501);
    bilnt_sp<<<dim3(3, 3, GB), 256, 0, stream>>>(
        Th, Tl, FAh + KA, FAl + KA, NPA, outp, bilbf, 2, g0, 1);
  }
}